// Round 6
// baseline (265.038 us; speedup 1.0000x reference)
//
#include <hip/hip_runtime.h>
#include <cstdint>
#include <cstddef>
#include <math.h>

#define B_   2
#define T_   2048
#define DM   1024
#define NH   16
#define DH   64
#define DC1  384
#define DCC  256
#define DR   32
#define BT   (B_*T_)
#define DQK  96      // DH + DR

typedef __bf16 bf16x8 __attribute__((ext_vector_type(8)));
typedef __bf16 bf16x4 __attribute__((ext_vector_type(4)));
typedef float  f32x4  __attribute__((ext_vector_type(4)));
typedef short  s16x4  __attribute__((ext_vector_type(4)));
#define MFMA16(a,b,c) __builtin_amdgcn_mfma_f32_16x16x32_bf16((a),(b),(c),0,0,0)

// 16x16x16 bf16 MFMA (K=16): A/B = 4 bf16 (2 VGPR), C/D = 4 f32.
// C/D layout is shape-determined, same as 16x16x32 (row=g*4+r, col=ln).
__device__ __forceinline__ f32x4 mfma_pv(bf16x4 a, bf16x4 b, f32x4 c) {
#if __has_builtin(__builtin_amdgcn_mfma_f32_16x16x16bf16_1k)
  return __builtin_amdgcn_mfma_f32_16x16x16bf16_1k(
      __builtin_bit_cast(s16x4, a), __builtin_bit_cast(s16x4, b), c, 0, 0, 0);
#else
  f32x4 d = c;
  asm volatile("v_mfma_f32_16x16x16_bf16 %0, %1, %2, %0"
               : "+v"(d) : "v"(a), "v"(b));
  return d;
#endif
}

__device__ __forceinline__ void gld16(const __bf16* g, __bf16* l) {
  __builtin_amdgcn_global_load_lds(
      (const __attribute__((address_space(1))) void*)g,
      (__attribute__((address_space(3))) void*)l, 16, 0, 0);
}

struct GemmDesc {
  const __bf16* A;
  const __bf16* Bt;
  void* C;
  int lda, ldb, ldc, K, Nvalid, ntx, blk0;
};
struct GemmBatch { GemmDesc d[4]; int nd; };

// ---------------------------------------------------------------------------
// Multi-GEMM, single-barrier double-buffered gld16 pipeline, BK=64, 4 waves.
// PROVEN CORRECT (r10-r12 bit-identical experiment). TM,TN in {64,128}.
// ---------------------------------------------------------------------------
template<typename CT, int TM, int TN>
__global__ __launch_bounds__(256) void gemm_multi(GemmBatch gb) {
  constexpr int MT  = TM / 32;
  constexpr int NT  = TN / 32;
  constexpr int APW = (TM * 4) / 256;
  constexpr int BPW = (TN * 4) / 256;
  __shared__ __align__(16) __bf16 As[4 * TM * 32];
  __shared__ __align__(16) __bf16 Bs[4 * TN * 32];
  const int bid = blockIdx.x;
  int di = gb.nd - 1;
  while (di > 0 && bid < gb.d[di].blk0) di--;
  const GemmDesc D = gb.d[di];
  const int local = bid - D.blk0;
  const int by = local / D.ntx, bx = local - by * D.ntx;
  const int m0 = by * TM, n0 = bx * TN;

  const int tid = threadIdx.x;
  const int w = tid >> 6, l = tid & 63;
  const int g = l >> 4, ln = l & 15;
  const int wm = w >> 1, wn = w & 1;

  const __bf16* gA[APW]; int aoff[APW];
  #pragma unroll
  for (int i = 0; i < APW; i++) {
    int slot = w * (APW * 64) + i * 64 + l;
    gA[i] = D.A + (size_t)(m0 + (slot >> 2)) * D.lda + (slot & 3) * 8;
    aoff[i] = (w * (APW * 64) + i * 64) * 8;
  }
  const __bf16* gB[BPW]; int boff[BPW];
  #pragma unroll
  for (int i = 0; i < BPW; i++) {
    int slot = w * (BPW * 64) + i * 64 + l;
    int bn = n0 + (slot >> 2); if (bn >= D.Nvalid) bn = D.Nvalid - 1;
    gB[i] = D.Bt + (size_t)bn * D.ldb + (slot & 3) * 8;
    boff[i] = (w * (BPW * 64) + i * 64) * 8;
  }

  f32x4 acc[MT][NT];
  #pragma unroll
  for (int i = 0; i < MT; i++)
    #pragma unroll
    for (int j = 0; j < NT; j++) acc[i][j] = (f32x4){0.f, 0.f, 0.f, 0.f};

  #pragma unroll
  for (int ch = 0; ch < 2; ch++) {
    #pragma unroll
    for (int i = 0; i < APW; i++)
      gld16(gA[i] + ch * 32, As + ch * TM * 32 + aoff[i]);
    #pragma unroll
    for (int i = 0; i < BPW; i++)
      gld16(gB[i] + ch * 32, Bs + ch * TN * 32 + boff[i]);
  }

  const int nper = D.K >> 6;
  int p = 0;
  for (int it = 0; it < nper; ++it) {
    __syncthreads();
    if (it + 1 < nper) {
      const int ko = (it + 1) * 64;
      #pragma unroll
      for (int ch = 0; ch < 2; ch++) {
        #pragma unroll
        for (int i = 0; i < APW; i++)
          gld16(gA[i] + ko + ch * 32, As + ((p ^ 1) * 2 + ch) * TM * 32 + aoff[i]);
        #pragma unroll
        for (int i = 0; i < BPW; i++)
          gld16(gB[i] + ko + ch * 32, Bs + ((p ^ 1) * 2 + ch) * TN * 32 + boff[i]);
      }
    }
    #pragma unroll
    for (int ch = 0; ch < 2; ch++) {
      bf16x8 af[MT], bfr[NT];
      #pragma unroll
      for (int mt = 0; mt < MT; mt++)
        af[mt] = *(const bf16x8*)(As + (p * 2 + ch) * TM * 32 +
                                  (wm * (TM/2) + mt * 16 + ln) * 32 + g * 8);
      #pragma unroll
      for (int nt = 0; nt < NT; nt++)
        bfr[nt] = *(const bf16x8*)(Bs + (p * 2 + ch) * TN * 32 +
                                   (wn * (TN/2) + nt * 16 + ln) * 32 + g * 8);
      #pragma unroll
      for (int mt = 0; mt < MT; mt++)
        #pragma unroll
        for (int nt = 0; nt < NT; nt++)
          acc[mt][nt] = MFMA16(af[mt], bfr[nt], acc[mt][nt]);
    }
    p ^= 1;
  }

  CT* C = (CT*)D.C;
  #pragma unroll
  for (int mt = 0; mt < MT; mt++)
    #pragma unroll
    for (int r = 0; r < 4; r++) {
      int m = m0 + wm * (TM/2) + mt * 16 + g * 4 + r;
      #pragma unroll
      for (int nt = 0; nt < NT; nt++) {
        int n = n0 + wn * (TN/2) + nt * 16 + ln;
        if (n < D.Nvalid) C[(size_t)m * D.ldc + n] = (CT)acc[mt][nt][r];
      }
    }
}

// ---------------------------------------------------------------------------
// Fused weight prep: 8 matrices fp32 [K,N] -> bf16 transposed [N,K].
// ---------------------------------------------------------------------------
struct TDescs {
  const float* src[8];
  __bf16* dst[8];
  int K[8];
  int N[8];
  int t0[9];
};

__global__ __launch_bounds__(256) void transpose_cast_all(TDescs td) {
  __shared__ float t[32][33];
  int bx = blockIdx.x;
  int i = 7;
  while (bx < td.t0[i]) i--;
  int local = bx - td.t0[i];
  int ntn = td.N[i] >> 5;
  int kt = local / ntn;
  int nt = local - kt * ntn;
  const int ks = kt * 32, ns = nt * 32;
  const float* src = td.src[i];
  __bf16* dst = td.dst[i];
  const int K = td.K[i], N = td.N[i];
  const int tx = threadIdx.x, ty = threadIdx.y;
  #pragma unroll
  for (int r = 0; r < 4; r++)
    t[ty + r * 8][tx] = src[(size_t)(ks + ty + r * 8) * N + ns + tx];
  __syncthreads();
  #pragma unroll
  for (int r = 0; r < 4; r++)
    dst[(size_t)(ns + ty + r * 8) * K + ks + tx] = (__bf16)t[tx][ty + r * 8];
  (void)K;
}

__global__ __launch_bounds__(256) void cast_f32_bf16(
    const float* __restrict__ src, __bf16* __restrict__ dst) {
  int i = (blockIdx.x * 256 + threadIdx.x) * 4;
  float4 v = *(const float4*)(src + i);
  bf16x4 o = { (__bf16)v.x, (__bf16)v.y, (__bf16)v.z, (__bf16)v.w };
  *(bf16x4*)(dst + i) = o;
}

// ---------------------------------------------------------------------------
// Assemble: per (row, head) wave -> RoPE + concat + RMS-norm.
// ---------------------------------------------------------------------------
__global__ __launch_bounds__(256) void assemble_qk(
    const __bf16* __restrict__ qsqr,  // [BT][1536]: qs | qr
    const __bf16* __restrict__ kv,    // [BT][1024]: ks
    const __bf16* __restrict__ cqkr,  // [BT][672]: kr at cols 640..671
    __bf16* __restrict__ qb, __bf16* __restrict__ kb) {
  int wid  = (blockIdx.x * blockDim.x + threadIdx.x) >> 6;
  int lane = threadIdx.x & 63;
  int h   = wid & (NH - 1);
  int row = wid >> 4;
  int b   = row >> 11;
  int t   = row & (T_ - 1);

  float v0q = (float)qsqr[(size_t)row * 1536 + h * DH + lane];
  float v0k = (float)kv[(size_t)row * 1024 + h * DH + lane];
  float v1q = 0.f, v1k = 0.f;
  if (lane < DR) {
    int j  = lane;
    int jj = j & 15;
    float invf = exp2f((float)jj * -0.8304820237f);  // 10000^(-jj/16)
    float ang  = (float)t * invf;
    float s, c;
    sincosf(ang, &s, &c);
    float qx1 = (float)qsqr[(size_t)row * 1536 + 1024 + h * DR + jj];
    float qx2 = (float)qsqr[(size_t)row * 1536 + 1024 + h * DR + 16 + jj];
    float kx1 = (float)cqkr[(size_t)row * 672 + 640 + jj];
    float kx2 = (float)cqkr[(size_t)row * 672 + 640 + 16 + jj];
    if (j < 16) { v1q = qx1 * c - qx2 * s; v1k = kx1 * c - kx2 * s; }
    else        { v1q = qx1 * s + qx2 * c; v1k = kx1 * s + kx2 * c; }
  }
  float ssq = v0q * v0q + v1q * v1q;
  float ssk = v0k * v0k + v1k * v1k;
  #pragma unroll
  for (int off = 32; off; off >>= 1) {
    ssq += __shfl_xor(ssq, off);
    ssk += __shfl_xor(ssk, off);
  }
  float sq = rsqrtf(ssq / 96.f + 1e-6f);
  float sk = rsqrtf(ssk / 96.f + 1e-6f);
  size_t obase = ((size_t)(b * NH + h) * T_ + t) * DQK;
  qb[obase + lane] = (__bf16)(v0q * sq);
  kb[obase + lane] = (__bf16)(v0k * sk);
  if (lane < DR) {
    qb[obase + DH + lane] = (__bf16)(v1q * sq);
    kb[obase + DH + lane] = (__bf16)(v1k * sk);
  }
}

// ---------------------------------------------------------------------------
// Fixed-max MFMA flash attention (causal), ONE tile per block, 4-wave blocks.
// r21: un-paired. Round-5 accounting: paired light/heavy blocks average only
// ~74% compute-wave utilization (light waves idle through heavy iterations).
// Now each block owns one 64-query tile (4 waves x 16 q), grid 32x32=1024
// blocks dispatched longest-first (tile = 31-bx). Every wave computes every
// iteration -- the causal-skip branch disappears (k0 <= tile*64 <= qw always).
// Same swapped-QK reg-P compute (r19) + dbuf single-barrier loop (r20).
// Staging redistributed to 256 threads: 3 K-slots + 2 V-slots per thread.
// ---------------------------------------------------------------------------
#define KS_STR 104   // K LDS row stride
#define VT_STR 72    // V^T LDS row stride
__global__ __launch_bounds__(256) void flash_mfma(
    const __bf16* __restrict__ qg, const __bf16* __restrict__ kg,
    const __bf16* __restrict__ vt,  // [b*1024 + h*64 + d][T_]  (V^T)
    __bf16* __restrict__ ao) {
  __shared__ __align__(16) __bf16 Ksh[2][64 * KS_STR];   // 2 x 13312 B
  __shared__ __align__(16) __bf16 Vth[2][64 * VT_STR];   // 2 x  9216 B

  const int hb = blockIdx.y;
  const int bb = hb >> 4, h = hb & 15;
  const int tile = (T_ / 64 - 1) - blockIdx.x;   // 31..0, longest first
  const int w    = threadIdx.x >> 6;             // 0..3
  const int lane = threadIdx.x & 63;
  const int g    = lane >> 4;
  const int ln   = lane & 15;
  const int qw   = tile * 64 + w * 16;           // wave's 16 queries
  const float scale = 0.10206207261596577f;      // 1/sqrt(96)
  const size_t hbT = (size_t)hb * T_;
  const __bf16* vrow = vt + (size_t)(bb * 1024 + h * 64) * T_;

  // staging: 256 threads; K = 768 bf16x8 slots (3/thread), V = 512 (2/thread)
  int krow[3], kcol[3];
  #pragma unroll
  for (int j = 0; j < 3; j++) {
    int id = j * 256 + (int)threadIdx.x;
    krow[j] = id / 12; kcol[j] = id % 12;
  }
  int vr[2], vc[2];
  #pragma unroll
  for (int j = 0; j < 2; j++) {
    int id = j * 256 + (int)threadIdx.x;
    vr[j] = id >> 3; vc[j] = id & 7;
  }

  bf16x8 qf[3];
  #pragma unroll
  for (int s = 0; s < 3; s++)
    qf[s] = *(const bf16x8*)(qg + (hbT + qw + ln) * DQK + s * 32 + g * 8);

  f32x4 o[4];
  #pragma unroll
  for (int nt = 0; nt < 4; nt++) o[nt] = (f32x4){0.f, 0.f, 0.f, 0.f};
  float lsum = 0.f;

  const int kmax = (tile + 1) * 64;

  bf16x8 kreg[3], vreg[2];
  // Prologue: tile 0 -> buf 0
  #pragma unroll
  for (int j = 0; j < 3; j++)
    kreg[j] = *(const bf16x8*)(kg + (hbT + krow[j]) * DQK + kcol[j] * 8);
  #pragma unroll
  for (int j = 0; j < 2; j++)
    vreg[j] = *(const bf16x8*)(vrow + (size_t)vr[j] * T_ + vc[j] * 8);
  #pragma unroll
  for (int j = 0; j < 3; j++)
    *(bf16x8*)(Ksh[0] + krow[j] * KS_STR + kcol[j] * 8) = kreg[j];
  #pragma unroll
  for (int j = 0; j < 2; j++)
    *(bf16x8*)(Vth[0] + vr[j] * VT_STR + vc[j] * 8) = vreg[j];
  __syncthreads();

  int p = 0;
  for (int k0 = 0; k0 < kmax; k0 += 64) {
    const bool havenext = (k0 + 64 < kmax);
    if (havenext) {   // prefetch next tile into regs (hidden by compute)
      #pragma unroll
      for (int j = 0; j < 3; j++)
        kreg[j] = *(const bf16x8*)(kg + (hbT + k0 + 64 + krow[j]) * DQK + kcol[j] * 8);
      #pragma unroll
      for (int j = 0; j < 2; j++)
        vreg[j] = *(const bf16x8*)(vrow + (size_t)vr[j] * T_ + k0 + 64 + vc[j] * 8);
    }

    {
      const __bf16* Kp = Ksh[p];
      const __bf16* Vp = Vth[p];
      // QK^T swapped: sa[ks] = S^T tile, row=key k0+ks*16+g*4+r, col=q=qw+ln
      f32x4 sa[4];
      #pragma unroll
      for (int ks = 0; ks < 4; ks++) sa[ks] = (f32x4){0.f, 0.f, 0.f, 0.f};
      #pragma unroll
      for (int s = 0; s < 3; s++)
        #pragma unroll
        for (int ks = 0; ks < 4; ks++) {
          bf16x8 kf = *(const bf16x8*)(Kp + (ks * 16 + ln) * KS_STR + s * 32 + g * 8);
          sa[ks] = MFMA16(kf, qf[s], sa[ks]);
        }
      const bool diag = (k0 + 63 > qw);   // true only on the last iteration
      bf16x4 bq[4];
      #pragma unroll
      for (int ks = 0; ks < 4; ks++)
        #pragma unroll
        for (int r = 0; r < 4; r++) {
          float pe = __expf(sa[ks][r] * scale);
          if (diag) {
            int key = k0 + ks * 16 + g * 4 + r;
            if (key > qw + ln) pe = 0.f;
          }
          lsum += pe;
          bq[ks][r] = (__bf16)pe;
        }
      // PV: O^T = V^T . P^T via 16x16x16 MFMA; B-frag = lane's own bq[ks].
      #pragma unroll
      for (int ks = 0; ks < 4; ks++)
        #pragma unroll
        for (int nt = 0; nt < 4; nt++) {
          bf16x4 vf = *(const bf16x4*)(Vp + (nt * 16 + ln) * VT_STR + ks * 16 + g * 4);
          o[nt] = mfma_pv(vf, bq[ks], o[nt]);
        }
    }

    if (havenext) {   // write next tile into the other buffer
      #pragma unroll
      for (int j = 0; j < 3; j++)
        *(bf16x8*)(Ksh[p ^ 1] + krow[j] * KS_STR + kcol[j] * 8) = kreg[j];
      #pragma unroll
      for (int j = 0; j < 2; j++)
        *(bf16x8*)(Vth[p ^ 1] + vr[j] * VT_STR + vc[j] * 8) = vreg[j];
    }
    __syncthreads();
    p ^= 1;
  }

  float s = lsum;
  s += __shfl_xor(s, 16);
  s += __shfl_xor(s, 32);
  const float linv = 1.0f / s;

  const size_t obase = (size_t)(bb * T_ + qw + ln) * DM + h * DH;
  #pragma unroll
  for (int nt = 0; nt < 4; nt++) {
    bf16x4 ov = { (__bf16)(o[nt][0] * linv), (__bf16)(o[nt][1] * linv),
                  (__bf16)(o[nt][2] * linv), (__bf16)(o[nt][3] * linv) };
    *(bf16x4*)(ao + obase + nt * 16 + g * 4) = ov;
  }
}

// ---------------------------------------------------------------------------
extern "C" void kernel_launch(void* const* d_in, const int* in_sizes, int n_in,
                              void* d_out, int out_size, void* d_ws, size_t ws_size,
                              hipStream_t stream) {
  const float* x     = (const float*)d_in[0];
  const float* w_dq  = (const float*)d_in[1];
  const float* w_uq  = (const float*)d_in[2];
  const float* w_rq  = (const float*)d_in[3];
  const float* w_dkv = (const float*)d_in[4];
  const float* w_rk  = (const float*)d_in[5];
  const float* w_uk  = (const float*)d_in[6];
  const float* w_uv  = (const float*)d_in[7];
  const float* w_o   = (const float*)d_in[8];
  float* out = (float*)d_out;

  __bf16* p = (__bf16*)d_ws;
  __bf16* xb   = p;  p += (size_t)BT * DM;
  __bf16* B1t  = p;  p += (size_t)672 * 1024;
  __bf16* B2t  = p;  p += (size_t)1536 * 384;
  __bf16* B3t  = p;  p += (size_t)2048 * 256;   // w_uk^T | w_uv^T
  __bf16* B4t  = p;  p += (size_t)1024 * 1024;
  __bf16* cqkr = p;  p += (size_t)BT * 672;     // c_q | c_kv | kr
  __bf16* qsqr = p;  p += (size_t)BT * 1536;    // qs | qr
  __bf16* kv   = p;  p += (size_t)BT * 1024;    // ks
  __bf16* vt   = p;  p += (size_t)BT * 1024;    // V^T [b*1024+h*64+d][T]
  __bf16* qb   = p;  p += (size_t)B_ * NH * T_ * DQK;
  __bf16* kb   = p;  p += (size_t)B_ * NH * T_ * DQK;
  __bf16* aob  = xb;   // xb dead after G1

  // Prep: cast x; fused transpose of all 8 weights
  cast_f32_bf16<<<(BT * DM) / 1024, 256, 0, stream>>>(x, xb);
  {
    TDescs td;
    const float* srcs[8] = {w_dq, w_dkv, w_rk, w_uq, w_rq, w_uk, w_uv, w_o};
    __bf16* dsts[8] = {B1t, B1t + (size_t)384 * 1024, B1t + (size_t)640 * 1024,
                       B2t, B2t + (size_t)1024 * 384,
                       B3t, B3t + (size_t)1024 * 256, B4t};
    int Ks[8] = {1024, 1024, 1024, 384, 384, 256, 256, 1024};
    int Ns[8] = {384, 256, 32, 1024, 512, 1024, 1024, 1024};
    int acc = 0;
    for (int i = 0; i < 8; i++) {
      td.src[i] = srcs[i]; td.dst[i] = dsts[i];
      td.K[i] = Ks[i]; td.N[i] = Ns[i];
      td.t0[i] = acc;
      acc += (Ks[i] / 32) * (Ns[i] / 32);
    }
    td.t0[8] = acc;
    transpose_cast_all<<<acc, dim3(32, 8), 0, stream>>>(td);
  }

  // G1: cqkr = xb @ B1t^T   (64x64, BK=64, 4-wave: 704 blocks)  [r14 proven]
  {
    GemmBatch g; g.nd = 1;
    g.d[0] = GemmDesc{xb, B1t, (void*)cqkr, DM, 1024, 672, 1024, 672, 11, 0};
    gemm_multi<__bf16, 64, 64><<<704, 256, 0, stream>>>(g);
  }
  // Fused: G2, G3, VT b0/b1 -> 128x128 tiles (m97 density): 896 blocks
  {
    GemmBatch g; g.nd = 4;
    g.d[0] = GemmDesc{cqkr, B2t, (void*)qsqr, 672, 384, 1536, 384, 1536, 12, 0};
    g.d[1] = GemmDesc{cqkr + 384, B3t, (void*)kv, 672, 256, 1024, 256, 1024, 8, 384};
    g.d[2] = GemmDesc{B3t + (size_t)1024 * 256, cqkr + 384, (void*)vt,
                      256, 672, T_, 256, T_, 16, 640};
    g.d[3] = GemmDesc{B3t + (size_t)1024 * 256, cqkr + (size_t)T_ * 672 + 384,
                      (void*)(vt + (size_t)1024 * T_), 256, 672, T_, 256, T_, 16, 768};
    gemm_multi<__bf16, 128, 128><<<896, 256, 0, stream>>>(g);
  }

  // RoPE + concat + RMS-norm
  assemble_qk<<<(BT * NH) / 4, 256, 0, stream>>>(qsqr, kv, cqkr, qb, kb);

  // Un-paired fixed-max causal MFMA flash attention (4-wave, 1024 blocks)
  flash_mfma<<<dim3(T_ / 64, B_ * NH), 256, 0, stream>>>(qb, kb, vt, aob);

  // G4: out = aob @ B4t^T  (fp32 out, 64x64, BK=64, 4-wave: 1024 blocks) [r14]
  {
    GemmBatch g; g.nd = 1;
    g.d[0] = GemmDesc{aob, B4t, (void*)out, DM, 1024, DM, 1024, 1024, 16, 0};
    gemm_multi<float, 64, 64><<<1024, 256, 0, stream>>>(g);
  }
}

// Round 7
// 221.075 us; speedup vs baseline: 1.1989x; 1.1989x over previous
//
#include <hip/hip_runtime.h>
#include <cstdint>
#include <cstddef>
#include <math.h>

#define B_   2
#define T_   2048
#define DM   1024
#define NH   16
#define DH   64
#define DC1  384
#define DCC  256
#define DR   32
#define BT   (B_*T_)
#define DQK  96      // DH + DR

typedef __bf16 bf16x8 __attribute__((ext_vector_type(8)));
typedef __bf16 bf16x4 __attribute__((ext_vector_type(4)));
typedef float  f32x4  __attribute__((ext_vector_type(4)));
typedef short  s16x4  __attribute__((ext_vector_type(4)));
#define MFMA16(a,b,c) __builtin_amdgcn_mfma_f32_16x16x32_bf16((a),(b),(c),0,0,0)

// 16x16x16 bf16 MFMA (K=16): A/B = 4 bf16 (2 VGPR), C/D = 4 f32.
// C/D layout is shape-determined, same as 16x16x32 (row=g*4+r, col=ln).
__device__ __forceinline__ f32x4 mfma_pv(bf16x4 a, bf16x4 b, f32x4 c) {
#if __has_builtin(__builtin_amdgcn_mfma_f32_16x16x16bf16_1k)
  return __builtin_amdgcn_mfma_f32_16x16x16bf16_1k(
      __builtin_bit_cast(s16x4, a), __builtin_bit_cast(s16x4, b), c, 0, 0, 0);
#else
  f32x4 d = c;
  asm volatile("v_mfma_f32_16x16x16_bf16 %0, %1, %2, %0"
               : "+v"(d) : "v"(a), "v"(b));
  return d;
#endif
}

__device__ __forceinline__ void gld16(const __bf16* g, __bf16* l) {
  __builtin_amdgcn_global_load_lds(
      (const __attribute__((address_space(1))) void*)g,
      (__attribute__((address_space(3))) void*)l, 16, 0, 0);
}

struct GemmDesc {
  const __bf16* A;
  const __bf16* Bt;
  void* C;
  int lda, ldb, ldc, K, Nvalid, ntx, blk0;
};
struct GemmBatch { GemmDesc d[4]; int nd; };

// ---------------------------------------------------------------------------
// Multi-GEMM, single-barrier double-buffered gld16 pipeline, BK=64, 4 waves.
// PROVEN CORRECT (r10-r12 bit-identical experiment). TM,TN in {64,128}.
// ---------------------------------------------------------------------------
template<typename CT, int TM, int TN>
__global__ __launch_bounds__(256) void gemm_multi(GemmBatch gb) {
  constexpr int MT  = TM / 32;
  constexpr int NT  = TN / 32;
  constexpr int APW = (TM * 4) / 256;
  constexpr int BPW = (TN * 4) / 256;
  __shared__ __align__(16) __bf16 As[4 * TM * 32];
  __shared__ __align__(16) __bf16 Bs[4 * TN * 32];
  const int bid = blockIdx.x;
  int di = gb.nd - 1;
  while (di > 0 && bid < gb.d[di].blk0) di--;
  const GemmDesc D = gb.d[di];
  const int local = bid - D.blk0;
  const int by = local / D.ntx, bx = local - by * D.ntx;
  const int m0 = by * TM, n0 = bx * TN;

  const int tid = threadIdx.x;
  const int w = tid >> 6, l = tid & 63;
  const int g = l >> 4, ln = l & 15;
  const int wm = w >> 1, wn = w & 1;

  const __bf16* gA[APW]; int aoff[APW];
  #pragma unroll
  for (int i = 0; i < APW; i++) {
    int slot = w * (APW * 64) + i * 64 + l;
    gA[i] = D.A + (size_t)(m0 + (slot >> 2)) * D.lda + (slot & 3) * 8;
    aoff[i] = (w * (APW * 64) + i * 64) * 8;
  }
  const __bf16* gB[BPW]; int boff[BPW];
  #pragma unroll
  for (int i = 0; i < BPW; i++) {
    int slot = w * (BPW * 64) + i * 64 + l;
    int bn = n0 + (slot >> 2); if (bn >= D.Nvalid) bn = D.Nvalid - 1;
    gB[i] = D.Bt + (size_t)bn * D.ldb + (slot & 3) * 8;
    boff[i] = (w * (BPW * 64) + i * 64) * 8;
  }

  f32x4 acc[MT][NT];
  #pragma unroll
  for (int i = 0; i < MT; i++)
    #pragma unroll
    for (int j = 0; j < NT; j++) acc[i][j] = (f32x4){0.f, 0.f, 0.f, 0.f};

  #pragma unroll
  for (int ch = 0; ch < 2; ch++) {
    #pragma unroll
    for (int i = 0; i < APW; i++)
      gld16(gA[i] + ch * 32, As + ch * TM * 32 + aoff[i]);
    #pragma unroll
    for (int i = 0; i < BPW; i++)
      gld16(gB[i] + ch * 32, Bs + ch * TN * 32 + boff[i]);
  }

  const int nper = D.K >> 6;
  int p = 0;
  for (int it = 0; it < nper; ++it) {
    __syncthreads();
    if (it + 1 < nper) {
      const int ko = (it + 1) * 64;
      #pragma unroll
      for (int ch = 0; ch < 2; ch++) {
        #pragma unroll
        for (int i = 0; i < APW; i++)
          gld16(gA[i] + ko + ch * 32, As + ((p ^ 1) * 2 + ch) * TM * 32 + aoff[i]);
        #pragma unroll
        for (int i = 0; i < BPW; i++)
          gld16(gB[i] + ko + ch * 32, Bs + ((p ^ 1) * 2 + ch) * TN * 32 + boff[i]);
      }
    }
    #pragma unroll
    for (int ch = 0; ch < 2; ch++) {
      bf16x8 af[MT], bfr[NT];
      #pragma unroll
      for (int mt = 0; mt < MT; mt++)
        af[mt] = *(const bf16x8*)(As + (p * 2 + ch) * TM * 32 +
                                  (wm * (TM/2) + mt * 16 + ln) * 32 + g * 8);
      #pragma unroll
      for (int nt = 0; nt < NT; nt++)
        bfr[nt] = *(const bf16x8*)(Bs + (p * 2 + ch) * TN * 32 +
                                   (wn * (TN/2) + nt * 16 + ln) * 32 + g * 8);
      #pragma unroll
      for (int mt = 0; mt < MT; mt++)
        #pragma unroll
        for (int nt = 0; nt < NT; nt++)
          acc[mt][nt] = MFMA16(af[mt], bfr[nt], acc[mt][nt]);
    }
    p ^= 1;
  }

  CT* C = (CT*)D.C;
  #pragma unroll
  for (int mt = 0; mt < MT; mt++)
    #pragma unroll
    for (int r = 0; r < 4; r++) {
      int m = m0 + wm * (TM/2) + mt * 16 + g * 4 + r;
      #pragma unroll
      for (int nt = 0; nt < NT; nt++) {
        int n = n0 + wn * (TN/2) + nt * 16 + ln;
        if (n < D.Nvalid) C[(size_t)m * D.ldc + n] = (CT)acc[mt][nt][r];
      }
    }
}

// ---------------------------------------------------------------------------
// Fused weight prep: 8 matrices fp32 [K,N] -> bf16 transposed [N,K].
// ---------------------------------------------------------------------------
struct TDescs {
  const float* src[8];
  __bf16* dst[8];
  int K[8];
  int N[8];
  int t0[9];
};

__global__ __launch_bounds__(256) void transpose_cast_all(TDescs td) {
  __shared__ float t[32][33];
  int bx = blockIdx.x;
  int i = 7;
  while (bx < td.t0[i]) i--;
  int local = bx - td.t0[i];
  int ntn = td.N[i] >> 5;
  int kt = local / ntn;
  int nt = local - kt * ntn;
  const int ks = kt * 32, ns = nt * 32;
  const float* src = td.src[i];
  __bf16* dst = td.dst[i];
  const int K = td.K[i], N = td.N[i];
  const int tx = threadIdx.x, ty = threadIdx.y;
  #pragma unroll
  for (int r = 0; r < 4; r++)
    t[ty + r * 8][tx] = src[(size_t)(ks + ty + r * 8) * N + ns + tx];
  __syncthreads();
  #pragma unroll
  for (int r = 0; r < 4; r++)
    dst[(size_t)(ns + ty + r * 8) * K + ks + tx] = (__bf16)t[tx][ty + r * 8];
  (void)K;
}

__global__ __launch_bounds__(256) void cast_f32_bf16(
    const float* __restrict__ src, __bf16* __restrict__ dst) {
  int i = (blockIdx.x * 256 + threadIdx.x) * 4;
  float4 v = *(const float4*)(src + i);
  bf16x4 o = { (__bf16)v.x, (__bf16)v.y, (__bf16)v.z, (__bf16)v.w };
  *(bf16x4*)(dst + i) = o;
}

// ---------------------------------------------------------------------------
// Assemble: per (row, head) wave -> RoPE + concat + RMS-norm.
// ---------------------------------------------------------------------------
__global__ __launch_bounds__(256) void assemble_qk(
    const __bf16* __restrict__ qsqr,  // [BT][1536]: qs | qr
    const __bf16* __restrict__ kv,    // [BT][1024]: ks
    const __bf16* __restrict__ cqkr,  // [BT][672]: kr at cols 640..671
    __bf16* __restrict__ qb, __bf16* __restrict__ kb) {
  int wid  = (blockIdx.x * blockDim.x + threadIdx.x) >> 6;
  int lane = threadIdx.x & 63;
  int h   = wid & (NH - 1);
  int row = wid >> 4;
  int b   = row >> 11;
  int t   = row & (T_ - 1);

  float v0q = (float)qsqr[(size_t)row * 1536 + h * DH + lane];
  float v0k = (float)kv[(size_t)row * 1024 + h * DH + lane];
  float v1q = 0.f, v1k = 0.f;
  if (lane < DR) {
    int j  = lane;
    int jj = j & 15;
    float invf = exp2f((float)jj * -0.8304820237f);  // 10000^(-jj/16)
    float ang  = (float)t * invf;
    float s, c;
    sincosf(ang, &s, &c);
    float qx1 = (float)qsqr[(size_t)row * 1536 + 1024 + h * DR + jj];
    float qx2 = (float)qsqr[(size_t)row * 1536 + 1024 + h * DR + 16 + jj];
    float kx1 = (float)cqkr[(size_t)row * 672 + 640 + jj];
    float kx2 = (float)cqkr[(size_t)row * 672 + 640 + 16 + jj];
    if (j < 16) { v1q = qx1 * c - qx2 * s; v1k = kx1 * c - kx2 * s; }
    else        { v1q = qx1 * s + qx2 * c; v1k = kx1 * s + kx2 * c; }
  }
  float ssq = v0q * v0q + v1q * v1q;
  float ssk = v0k * v0k + v1k * v1k;
  #pragma unroll
  for (int off = 32; off; off >>= 1) {
    ssq += __shfl_xor(ssq, off);
    ssk += __shfl_xor(ssk, off);
  }
  float sq = rsqrtf(ssq / 96.f + 1e-6f);
  float sk = rsqrtf(ssk / 96.f + 1e-6f);
  size_t obase = ((size_t)(b * NH + h) * T_ + t) * DQK;
  qb[obase + lane] = (__bf16)(v0q * sq);
  kb[obase + lane] = (__bf16)(v0k * sk);
  if (lane < DR) {
    qb[obase + DH + lane] = (__bf16)(v1q * sq);
    kb[obase + DH + lane] = (__bf16)(v1k * sk);
  }
}

// ---------------------------------------------------------------------------
// Fixed-max MFMA flash attention (causal), paired q-tiles, 8-wave blocks.
// r20 structure (proven 53.7 us): swapped-QK reg-P + dbuf single-barrier.
// r22: CU-load-balancing block remap. r20's bid = ta + 16*hb with 512 blocks
// (exactly 2/CU) put bid and bid+256 (same ta class, duration 32-ta) on the
// SAME CU slot (same bid%8 XCD, same in-XCD slot): per-CU load 2*(32-ta) ∈
// [34,64] iter-units, wall ~ 64 while mean is 49. Remap so the two halves
// carry complementary ta: first 256 bids ta=i&15, second 256 ta=15-(i&15)
// -> every CU pair sums to 49 (constant). Bijective relabeling only.
// ---------------------------------------------------------------------------
#define KS_STR 104   // K LDS row stride
#define VT_STR 72    // V^T LDS row stride
__global__ __launch_bounds__(512) void flash_mfma(
    const __bf16* __restrict__ qg, const __bf16* __restrict__ kg,
    const __bf16* __restrict__ vt,  // [b*1024 + h*64 + d][T_]  (V^T)
    __bf16* __restrict__ ao) {
  __shared__ __align__(16) __bf16 Ksh[2][64 * KS_STR];   // 2 x 13312 B
  __shared__ __align__(16) __bf16 Vth[2][64 * VT_STR];   // 2 x  9216 B

  // load-balanced remap: lb 0..511 -> (ta, hb); halves complementary in ta
  const int lb   = blockIdx.y * 16 + blockIdx.x;
  const int half = lb >> 8;            // 0 | 1
  const int i    = lb & 255;
  const int tc   = i & 15;
  const int ta   = half ? (15 - tc) : tc;        // light tile 0..15
  const int hb   = (i >> 4) + half * 16;         // head-batch 0..31
  const int tb   = (T_ / 64 - 1) - ta;           // heavy tile 31..16

  const int bb = hb >> 4, h = hb & 15;
  const int w    = threadIdx.x >> 6;         // 0..7
  const int lane = threadIdx.x & 63;
  const int g    = lane >> 4;
  const int ln   = lane & 15;
  const int wi   = w & 3;
  const int tile = (w < 4) ? tb : ta;        // wave's tile
  const int qw   = tile * 64 + wi * 16;      // wave's 16 queries
  const float scale = 0.10206207261596577f;  // 1/sqrt(96)
  const size_t hbT = (size_t)hb * T_;
  const __bf16* vrow = vt + (size_t)(bb * 1024 + h * 64) * T_;

  const int ks0   = threadIdx.x;
  const int krow0 = ks0 / 12, kcol0 = ks0 % 12;
  const bool k1on = (threadIdx.x < 256);
  const int ks1   = 512 + threadIdx.x;
  const int krow1 = ks1 / 12, kcol1 = ks1 % 12;
  const int vr = threadIdx.x >> 3, vc = threadIdx.x & 7;

  bf16x8 qf[3];
  #pragma unroll
  for (int s = 0; s < 3; s++)
    qf[s] = *(const bf16x8*)(qg + (hbT + qw + ln) * DQK + s * 32 + g * 8);

  f32x4 o[4];
  #pragma unroll
  for (int nt = 0; nt < 4; nt++) o[nt] = (f32x4){0.f, 0.f, 0.f, 0.f};
  float lsum = 0.f;

  const int kmax = (tb + 1) * 64;

  bf16x8 kreg0, kreg1, vreg;
  // Prologue: tile 0 -> buf 0
  kreg0 = *(const bf16x8*)(kg + (hbT + krow0) * DQK + kcol0 * 8);
  if (k1on) kreg1 = *(const bf16x8*)(kg + (hbT + krow1) * DQK + kcol1 * 8);
  vreg = *(const bf16x8*)(vrow + (size_t)vr * T_ + vc * 8);
  *(bf16x8*)(Ksh[0] + krow0 * KS_STR + kcol0 * 8) = kreg0;
  if (k1on) *(bf16x8*)(Ksh[0] + krow1 * KS_STR + kcol1 * 8) = kreg1;
  *(bf16x8*)(Vth[0] + vr * VT_STR + vc * 8) = vreg;
  __syncthreads();

  int p = 0;
  for (int k0 = 0; k0 < kmax; k0 += 64) {
    const bool havenext = (k0 + 64 < kmax);
    if (havenext) {   // prefetch next tile into regs (hidden by compute)
      kreg0 = *(const bf16x8*)(kg + (hbT + k0 + 64 + krow0) * DQK + kcol0 * 8);
      if (k1on)
        kreg1 = *(const bf16x8*)(kg + (hbT + k0 + 64 + krow1) * DQK + kcol1 * 8);
      vreg = *(const bf16x8*)(vrow + (size_t)vr * T_ + k0 + 64 + vc * 8);
    }

    if (k0 <= qw + 15) {   // wave-uniform causal skip
      const __bf16* Kp = Ksh[p];
      const __bf16* Vp = Vth[p];
      // QK^T swapped: sa[ks] = S^T tile, row=key k0+ks*16+g*4+r, col=q=qw+ln
      f32x4 sa[4];
      #pragma unroll
      for (int ks = 0; ks < 4; ks++) sa[ks] = (f32x4){0.f, 0.f, 0.f, 0.f};
      #pragma unroll
      for (int s = 0; s < 3; s++)
        #pragma unroll
        for (int ks = 0; ks < 4; ks++) {
          bf16x8 kf = *(const bf16x8*)(Kp + (ks * 16 + ln) * KS_STR + s * 32 + g * 8);
          sa[ks] = MFMA16(kf, qf[s], sa[ks]);
        }
      const bool diag = (k0 + 63 > qw);
      bf16x4 bq[4];
      #pragma unroll
      for (int ks = 0; ks < 4; ks++)
        #pragma unroll
        for (int r = 0; r < 4; r++) {
          float pe = __expf(sa[ks][r] * scale);
          if (diag) {
            int key = k0 + ks * 16 + g * 4 + r;
            if (key > qw + ln) pe = 0.f;
          }
          lsum += pe;
          bq[ks][r] = (__bf16)pe;
        }
      // PV: O^T = V^T . P^T via 16x16x16 MFMA; B-frag = lane's own bq[ks].
      #pragma unroll
      for (int ks = 0; ks < 4; ks++)
        #pragma unroll
        for (int nt = 0; nt < 4; nt++) {
          bf16x4 vf = *(const bf16x4*)(Vp + (nt * 16 + ln) * VT_STR + ks * 16 + g * 4);
          o[nt] = mfma_pv(vf, bq[ks], o[nt]);
        }
    }

    if (havenext) {   // write next tile into the other buffer
      *(bf16x8*)(Ksh[p ^ 1] + krow0 * KS_STR + kcol0 * 8) = kreg0;
      if (k1on) *(bf16x8*)(Ksh[p ^ 1] + krow1 * KS_STR + kcol1 * 8) = kreg1;
      *(bf16x8*)(Vth[p ^ 1] + vr * VT_STR + vc * 8) = vreg;
    }
    __syncthreads();
    p ^= 1;
  }

  float s = lsum;
  s += __shfl_xor(s, 16);
  s += __shfl_xor(s, 32);
  const float linv = 1.0f / s;

  const size_t obase = (size_t)(bb * T_ + qw + ln) * DM + h * DH;
  #pragma unroll
  for (int nt = 0; nt < 4; nt++) {
    bf16x4 ov = { (__bf16)(o[nt][0] * linv), (__bf16)(o[nt][1] * linv),
                  (__bf16)(o[nt][2] * linv), (__bf16)(o[nt][3] * linv) };
    *(bf16x4*)(ao + obase + nt * 16 + g * 4) = ov;
  }
}

// ---------------------------------------------------------------------------
extern "C" void kernel_launch(void* const* d_in, const int* in_sizes, int n_in,
                              void* d_out, int out_size, void* d_ws, size_t ws_size,
                              hipStream_t stream) {
  const float* x     = (const float*)d_in[0];
  const float* w_dq  = (const float*)d_in[1];
  const float* w_uq  = (const float*)d_in[2];
  const float* w_rq  = (const float*)d_in[3];
  const float* w_dkv = (const float*)d_in[4];
  const float* w_rk  = (const float*)d_in[5];
  const float* w_uk  = (const float*)d_in[6];
  const float* w_uv  = (const float*)d_in[7];
  const float* w_o   = (const float*)d_in[8];
  float* out = (float*)d_out;

  __bf16* p = (__bf16*)d_ws;
  __bf16* xb   = p;  p += (size_t)BT * DM;
  __bf16* B1t  = p;  p += (size_t)672 * 1024;
  __bf16* B2t  = p;  p += (size_t)1536 * 384;
  __bf16* B3t  = p;  p += (size_t)2048 * 256;   // w_uk^T | w_uv^T
  __bf16* B4t  = p;  p += (size_t)1024 * 1024;
  __bf16* cqkr = p;  p += (size_t)BT * 672;     // c_q | c_kv | kr
  __bf16* qsqr = p;  p += (size_t)BT * 1536;    // qs | qr
  __bf16* kv   = p;  p += (size_t)BT * 1024;    // ks
  __bf16* vt   = p;  p += (size_t)BT * 1024;    // V^T [b*1024+h*64+d][T]
  __bf16* qb   = p;  p += (size_t)B_ * NH * T_ * DQK;
  __bf16* kb   = p;  p += (size_t)B_ * NH * T_ * DQK;
  __bf16* aob  = xb;   // xb dead after G1

  // Prep: cast x; fused transpose of all 8 weights
  cast_f32_bf16<<<(BT * DM) / 1024, 256, 0, stream>>>(x, xb);
  {
    TDescs td;
    const float* srcs[8] = {w_dq, w_dkv, w_rk, w_uq, w_rq, w_uk, w_uv, w_o};
    __bf16* dsts[8] = {B1t, B1t + (size_t)384 * 1024, B1t + (size_t)640 * 1024,
                       B2t, B2t + (size_t)1024 * 384,
                       B3t, B3t + (size_t)1024 * 256, B4t};
    int Ks[8] = {1024, 1024, 1024, 384, 384, 256, 256, 1024};
    int Ns[8] = {384, 256, 32, 1024, 512, 1024, 1024, 1024};
    int acc = 0;
    for (int i = 0; i < 8; i++) {
      td.src[i] = srcs[i]; td.dst[i] = dsts[i];
      td.K[i] = Ks[i]; td.N[i] = Ns[i];
      td.t0[i] = acc;
      acc += (Ks[i] / 32) * (Ns[i] / 32);
    }
    td.t0[8] = acc;
    transpose_cast_all<<<acc, dim3(32, 8), 0, stream>>>(td);
  }

  // G1: cqkr = xb @ B1t^T   (64x64, BK=64, 4-wave: 704 blocks)  [r14 proven]
  {
    GemmBatch g; g.nd = 1;
    g.d[0] = GemmDesc{xb, B1t, (void*)cqkr, DM, 1024, 672, 1024, 672, 11, 0};
    gemm_multi<__bf16, 64, 64><<<704, 256, 0, stream>>>(g);
  }
  // Fused: G2, G3, VT b0/b1 -> 128x128 tiles (m97 density): 896 blocks
  {
    GemmBatch g; g.nd = 4;
    g.d[0] = GemmDesc{cqkr, B2t, (void*)qsqr, 672, 384, 1536, 384, 1536, 12, 0};
    g.d[1] = GemmDesc{cqkr + 384, B3t, (void*)kv, 672, 256, 1024, 256, 1024, 8, 384};
    g.d[2] = GemmDesc{B3t + (size_t)1024 * 256, cqkr + 384, (void*)vt,
                      256, 672, T_, 256, T_, 16, 640};
    g.d[3] = GemmDesc{B3t + (size_t)1024 * 256, cqkr + (size_t)T_ * 672 + 384,
                      (void*)(vt + (size_t)1024 * T_), 256, 672, T_, 256, T_, 16, 768};
    gemm_multi<__bf16, 128, 128><<<896, 256, 0, stream>>>(g);
  }

  // RoPE + concat + RMS-norm
  assemble_qk<<<(BT * NH) / 4, 256, 0, stream>>>(qsqr, kv, cqkr, qb, kb);

  // Paired-tile fixed-max causal MFMA flash attention (8-wave, balanced remap)
  flash_mfma<<<dim3(T_ / 128, B_ * NH), 512, 0, stream>>>(qb, kb, vt, aob);

  // G4: out = aob @ B4t^T  (fp32 out, 64x64, BK=64, 4-wave: 1024 blocks) [r14]
  {
    GemmBatch g; g.nd = 1;
    g.d[0] = GemmDesc{aob, B4t, (void*)out, DM, 1024, DM, 1024, 1024, 16, 0};
    gemm_multi<float, 64, 64><<<1024, 256, 0, stream>>>(g);
  }
}

// Round 8
// 215.562 us; speedup vs baseline: 1.2295x; 1.0256x over previous
//
#include <hip/hip_runtime.h>
#include <cstdint>
#include <cstddef>
#include <math.h>

#define B_   2
#define T_   2048
#define DM   1024
#define NH   16
#define DH   64
#define DC1  384
#define DCC  256
#define DR   32
#define BT   (B_*T_)
#define DQK  96      // DH + DR

typedef __bf16 bf16x8 __attribute__((ext_vector_type(8)));
typedef __bf16 bf16x4 __attribute__((ext_vector_type(4)));
typedef float  f32x4  __attribute__((ext_vector_type(4)));
typedef short  s16x4  __attribute__((ext_vector_type(4)));
#define MFMA16(a,b,c) __builtin_amdgcn_mfma_f32_16x16x32_bf16((a),(b),(c),0,0,0)

// 16x16x16 bf16 MFMA (K=16): A/B = 4 bf16 (2 VGPR), C/D = 4 f32.
__device__ __forceinline__ f32x4 mfma_pv(bf16x4 a, bf16x4 b, f32x4 c) {
#if __has_builtin(__builtin_amdgcn_mfma_f32_16x16x16bf16_1k)
  return __builtin_amdgcn_mfma_f32_16x16x16bf16_1k(
      __builtin_bit_cast(s16x4, a), __builtin_bit_cast(s16x4, b), c, 0, 0, 0);
#else
  f32x4 d = c;
  asm volatile("v_mfma_f32_16x16x16_bf16 %0, %1, %2, %0"
               : "+v"(d) : "v"(a), "v"(b));
  return d;
#endif
}

__device__ __forceinline__ float exp2_fast(float x) {
#if __has_builtin(__builtin_amdgcn_exp2f)
  return __builtin_amdgcn_exp2f(x);
#else
  float r; asm("v_exp_f32 %0, %1" : "=v"(r) : "v"(x)); return r;
#endif
}

__device__ __forceinline__ void gld16(const __bf16* g, __bf16* l) {
  __builtin_amdgcn_global_load_lds(
      (const __attribute__((address_space(1))) void*)g,
      (__attribute__((address_space(3))) void*)l, 16, 0, 0);
}

struct GemmDesc {
  const __bf16* A;
  const __bf16* Bt;
  void* C;
  int lda, ldb, ldc, K, Nvalid, ntx, blk0;
};
struct GemmBatch { GemmDesc d[4]; int nd; };

// ---------------------------------------------------------------------------
// Multi-GEMM, single-barrier double-buffered gld16 pipeline, BK=64, 4 waves.
// PROVEN CORRECT (r10-r12 bit-identical experiment). TM,TN in {64,128}.
// ---------------------------------------------------------------------------
template<typename CT, int TM, int TN>
__global__ __launch_bounds__(256) void gemm_multi(GemmBatch gb) {
  constexpr int MT  = TM / 32;
  constexpr int NT  = TN / 32;
  constexpr int APW = (TM * 4) / 256;
  constexpr int BPW = (TN * 4) / 256;
  __shared__ __align__(16) __bf16 As[4 * TM * 32];
  __shared__ __align__(16) __bf16 Bs[4 * TN * 32];
  const int bid = blockIdx.x;
  int di = gb.nd - 1;
  while (di > 0 && bid < gb.d[di].blk0) di--;
  const GemmDesc D = gb.d[di];
  const int local = bid - D.blk0;
  const int by = local / D.ntx, bx = local - by * D.ntx;
  const int m0 = by * TM, n0 = bx * TN;

  const int tid = threadIdx.x;
  const int w = tid >> 6, l = tid & 63;
  const int g = l >> 4, ln = l & 15;
  const int wm = w >> 1, wn = w & 1;

  const __bf16* gA[APW]; int aoff[APW];
  #pragma unroll
  for (int i = 0; i < APW; i++) {
    int slot = w * (APW * 64) + i * 64 + l;
    gA[i] = D.A + (size_t)(m0 + (slot >> 2)) * D.lda + (slot & 3) * 8;
    aoff[i] = (w * (APW * 64) + i * 64) * 8;
  }
  const __bf16* gB[BPW]; int boff[BPW];
  #pragma unroll
  for (int i = 0; i < BPW; i++) {
    int slot = w * (BPW * 64) + i * 64 + l;
    int bn = n0 + (slot >> 2); if (bn >= D.Nvalid) bn = D.Nvalid - 1;
    gB[i] = D.Bt + (size_t)bn * D.ldb + (slot & 3) * 8;
    boff[i] = (w * (BPW * 64) + i * 64) * 8;
  }

  f32x4 acc[MT][NT];
  #pragma unroll
  for (int i = 0; i < MT; i++)
    #pragma unroll
    for (int j = 0; j < NT; j++) acc[i][j] = (f32x4){0.f, 0.f, 0.f, 0.f};

  #pragma unroll
  for (int ch = 0; ch < 2; ch++) {
    #pragma unroll
    for (int i = 0; i < APW; i++)
      gld16(gA[i] + ch * 32, As + ch * TM * 32 + aoff[i]);
    #pragma unroll
    for (int i = 0; i < BPW; i++)
      gld16(gB[i] + ch * 32, Bs + ch * TN * 32 + boff[i]);
  }

  const int nper = D.K >> 6;
  int p = 0;
  for (int it = 0; it < nper; ++it) {
    __syncthreads();
    if (it + 1 < nper) {
      const int ko = (it + 1) * 64;
      #pragma unroll
      for (int ch = 0; ch < 2; ch++) {
        #pragma unroll
        for (int i = 0; i < APW; i++)
          gld16(gA[i] + ko + ch * 32, As + ((p ^ 1) * 2 + ch) * TM * 32 + aoff[i]);
        #pragma unroll
        for (int i = 0; i < BPW; i++)
          gld16(gB[i] + ko + ch * 32, Bs + ((p ^ 1) * 2 + ch) * TN * 32 + boff[i]);
      }
    }
    #pragma unroll
    for (int ch = 0; ch < 2; ch++) {
      bf16x8 af[MT], bfr[NT];
      #pragma unroll
      for (int mt = 0; mt < MT; mt++)
        af[mt] = *(const bf16x8*)(As + (p * 2 + ch) * TM * 32 +
                                  (wm * (TM/2) + mt * 16 + ln) * 32 + g * 8);
      #pragma unroll
      for (int nt = 0; nt < NT; nt++)
        bfr[nt] = *(const bf16x8*)(Bs + (p * 2 + ch) * TN * 32 +
                                   (wn * (TN/2) + nt * 16 + ln) * 32 + g * 8);
      #pragma unroll
      for (int mt = 0; mt < MT; mt++)
        #pragma unroll
        for (int nt = 0; nt < NT; nt++)
          acc[mt][nt] = MFMA16(af[mt], bfr[nt], acc[mt][nt]);
    }
    p ^= 1;
  }

  CT* C = (CT*)D.C;
  #pragma unroll
  for (int mt = 0; mt < MT; mt++)
    #pragma unroll
    for (int r = 0; r < 4; r++) {
      int m = m0 + wm * (TM/2) + mt * 16 + g * 4 + r;
      #pragma unroll
      for (int nt = 0; nt < NT; nt++) {
        int n = n0 + wn * (TN/2) + nt * 16 + ln;
        if (n < D.Nvalid) C[(size_t)m * D.ldc + n] = (CT)acc[mt][nt][r];
      }
    }
}

// ---------------------------------------------------------------------------
// Fused prep (r23): cast x -> bf16 AND transpose-cast all 8 weights in ONE
// launch (independent work; branch on blockIdx range). Saves a launch gap.
// ---------------------------------------------------------------------------
struct TDescs {
  const float* src[8];
  __bf16* dst[8];
  int K[8];
  int N[8];
  int t0[9];
};

__global__ __launch_bounds__(256) void prep_all(
    const float* __restrict__ x, __bf16* __restrict__ xb, TDescs td) {
  __shared__ float t[32][33];
  const int nCast = (BT * DM) / 1024;   // 4096 blocks of cast work
  if ((int)blockIdx.x < nCast) {
    int i = (blockIdx.x * 256 + threadIdx.x) * 4;
    float4 v = *(const float4*)(x + i);
    bf16x4 o = { (__bf16)v.x, (__bf16)v.y, (__bf16)v.z, (__bf16)v.w };
    *(bf16x4*)(xb + i) = o;
    return;
  }
  int bx = blockIdx.x - nCast;
  int i = 7;
  while (bx < td.t0[i]) i--;
  int local = bx - td.t0[i];
  int ntn = td.N[i] >> 5;
  int kt = local / ntn;
  int nt = local - kt * ntn;
  const int ks = kt * 32, ns = nt * 32;
  const float* src = td.src[i];
  __bf16* dst = td.dst[i];
  const int N = td.N[i], K = td.K[i];
  const int tx = threadIdx.x & 31, ty = threadIdx.x >> 5;
  #pragma unroll
  for (int r = 0; r < 4; r++)
    t[ty + r * 8][tx] = src[(size_t)(ks + ty + r * 8) * N + ns + tx];
  __syncthreads();
  #pragma unroll
  for (int r = 0; r < 4; r++)
    dst[(size_t)(ns + ty + r * 8) * K + ks + tx] = (__bf16)t[tx][ty + r * 8];
}

// ---------------------------------------------------------------------------
// Assemble: per (row, head) wave -> RoPE + concat + RMS-norm.
// r23: qb is pre-scaled by scale*log2(e) so flash's softmax is a bare exp2.
// ---------------------------------------------------------------------------
__global__ __launch_bounds__(256) void assemble_qk(
    const __bf16* __restrict__ qsqr,  // [BT][1536]: qs | qr
    const __bf16* __restrict__ kv,    // [BT][1024]: ks
    const __bf16* __restrict__ cqkr,  // [BT][672]: kr at cols 640..671
    __bf16* __restrict__ qb, __bf16* __restrict__ kb) {
  int wid  = (blockIdx.x * blockDim.x + threadIdx.x) >> 6;
  int lane = threadIdx.x & 63;
  int h   = wid & (NH - 1);
  int row = wid >> 4;
  int b   = row >> 11;
  int t   = row & (T_ - 1);

  float v0q = (float)qsqr[(size_t)row * 1536 + h * DH + lane];
  float v0k = (float)kv[(size_t)row * 1024 + h * DH + lane];
  float v1q = 0.f, v1k = 0.f;
  if (lane < DR) {
    int j  = lane;
    int jj = j & 15;
    float invf = exp2f((float)jj * -0.8304820237f);  // 10000^(-jj/16)
    float ang  = (float)t * invf;
    float s, c;
    sincosf(ang, &s, &c);
    float qx1 = (float)qsqr[(size_t)row * 1536 + 1024 + h * DR + jj];
    float qx2 = (float)qsqr[(size_t)row * 1536 + 1024 + h * DR + 16 + jj];
    float kx1 = (float)cqkr[(size_t)row * 672 + 640 + jj];
    float kx2 = (float)cqkr[(size_t)row * 672 + 640 + 16 + jj];
    if (j < 16) { v1q = qx1 * c - qx2 * s; v1k = kx1 * c - kx2 * s; }
    else        { v1q = qx1 * s + qx2 * c; v1k = kx1 * s + kx2 * c; }
  }
  float ssq = v0q * v0q + v1q * v1q;
  float ssk = v0k * v0k + v1k * v1k;
  #pragma unroll
  for (int off = 32; off; off >>= 1) {
    ssq += __shfl_xor(ssq, off);
    ssk += __shfl_xor(ssk, off);
  }
  float sq = rsqrtf(ssq / 96.f + 1e-6f);
  float sk = rsqrtf(ssk / 96.f + 1e-6f);
  // scale(1/sqrt(96)) * log2(e) folded into q so flash does p = exp2(sa)
  float sqq = sq * 0.14724431f;
  size_t obase = ((size_t)(b * NH + h) * T_ + t) * DQK;
  qb[obase + lane] = (__bf16)(v0q * sqq);
  kb[obase + lane] = (__bf16)(v0k * sk);
  if (lane < DR) {
    qb[obase + DH + lane] = (__bf16)(v1q * sqq);
    kb[obase + DH + lane] = (__bf16)(v1k * sk);
  }
}

// ---------------------------------------------------------------------------
// Fixed-max MFMA flash attention (causal), paired q-tiles, 8-wave blocks.
// r20 structure (proven 53.7): swapped-QK reg-P + dbuf single-barrier.
// r23: (a) k-permuted V LDS layout -- element (d,k) stored at
//   p(k) = (k&3) + 4*(k>>4) + 16*((k>>2)&3), so one lane's four PV fragments
//   (fixed g, ks=0..3) are 16 contiguous elements: V reads collapse from
//   16 ds_read_b64 to 4 ds_read_b128 per wave-iter (r7 accounting: LDS pipe
//   ~93% busy incl. conflicts -- this cuts read demand ~20%).
//   Writes: each staged bf16x8 (k=8vc..8vc+7 of row d) splits into two b64 at
//   pA = 4*(vc>>1)+32*(vc&1) and pA+16 (bijective, 8B-aligned).
// (b) softmax exp is a single v_exp (scale*log2e pre-folded into qb).
// ---------------------------------------------------------------------------
#define KS_STR 104   // K LDS row stride
#define VT_STR 72    // V LDS row stride (k-permuted layout, 64 used + 8 pad)
__global__ __launch_bounds__(512) void flash_mfma(
    const __bf16* __restrict__ qg, const __bf16* __restrict__ kg,
    const __bf16* __restrict__ vt,  // [b*1024 + h*64 + d][T_]  (V^T)
    __bf16* __restrict__ ao) {
  __shared__ __align__(16) __bf16 Ksh[2][64 * KS_STR];   // 2 x 13312 B
  __shared__ __align__(16) __bf16 Vth[2][64 * VT_STR];   // 2 x  9216 B

  // load-balanced remap (r22, neutral but kept): halves complementary in ta
  const int lb   = blockIdx.y * 16 + blockIdx.x;
  const int half = lb >> 8;
  const int i    = lb & 255;
  const int tc   = i & 15;
  const int ta   = half ? (15 - tc) : tc;        // light tile 0..15
  const int hb   = (i >> 4) + half * 16;         // head-batch 0..31
  const int tb   = (T_ / 64 - 1) - ta;           // heavy tile 31..16

  const int bb = hb >> 4, h = hb & 15;
  const int w    = threadIdx.x >> 6;         // 0..7
  const int lane = threadIdx.x & 63;
  const int g    = lane >> 4;
  const int ln   = lane & 15;
  const int wi   = w & 3;
  const int tile = (w < 4) ? tb : ta;        // wave's tile
  const int qw   = tile * 64 + wi * 16;      // wave's 16 queries
  const size_t hbT = (size_t)hb * T_;
  const __bf16* vrow = vt + (size_t)(bb * 1024 + h * 64) * T_;

  const int ks0   = threadIdx.x;
  const int krow0 = ks0 / 12, kcol0 = ks0 % 12;
  const bool k1on = (threadIdx.x < 256);
  const int ks1   = 512 + threadIdx.x;
  const int krow1 = ks1 / 12, kcol1 = ks1 % 12;
  const int vr = threadIdx.x >> 3, vc = threadIdx.x & 7;
  const int vpA = ((vc >> 1) << 2) | ((vc & 1) << 5);   // k-permuted base

  bf16x8 qf[3];
  #pragma unroll
  for (int s = 0; s < 3; s++)
    qf[s] = *(const bf16x8*)(qg + (hbT + qw + ln) * DQK + s * 32 + g * 8);

  f32x4 o[4];
  #pragma unroll
  for (int nt = 0; nt < 4; nt++) o[nt] = (f32x4){0.f, 0.f, 0.f, 0.f};
  float lsum = 0.f;

  const int kmax = (tb + 1) * 64;

  bf16x8 kreg0, kreg1, vreg;
  // Prologue: tile 0 -> buf 0
  kreg0 = *(const bf16x8*)(kg + (hbT + krow0) * DQK + kcol0 * 8);
  if (k1on) kreg1 = *(const bf16x8*)(kg + (hbT + krow1) * DQK + kcol1 * 8);
  vreg = *(const bf16x8*)(vrow + (size_t)vr * T_ + vc * 8);
  *(bf16x8*)(Ksh[0] + krow0 * KS_STR + kcol0 * 8) = kreg0;
  if (k1on) *(bf16x8*)(Ksh[0] + krow1 * KS_STR + kcol1 * 8) = kreg1;
  {
    __bf16* vd = Vth[0] + vr * VT_STR + vpA;
    *(bf16x4*)(vd)      = __builtin_shufflevector(vreg, vreg, 0, 1, 2, 3);
    *(bf16x4*)(vd + 16) = __builtin_shufflevector(vreg, vreg, 4, 5, 6, 7);
  }
  __syncthreads();

  int p = 0;
  for (int k0 = 0; k0 < kmax; k0 += 64) {
    const bool havenext = (k0 + 64 < kmax);
    if (havenext) {   // prefetch next tile into regs (hidden by compute)
      kreg0 = *(const bf16x8*)(kg + (hbT + k0 + 64 + krow0) * DQK + kcol0 * 8);
      if (k1on)
        kreg1 = *(const bf16x8*)(kg + (hbT + k0 + 64 + krow1) * DQK + kcol1 * 8);
      vreg = *(const bf16x8*)(vrow + (size_t)vr * T_ + k0 + 64 + vc * 8);
    }

    if (k0 <= qw + 15) {   // wave-uniform causal skip
      const __bf16* Kp = Ksh[p];
      const __bf16* Vp = Vth[p];
      // QK^T swapped: sa[ks] = S^T tile, row=key k0+ks*16+g*4+r, col=q=qw+ln
      f32x4 sa[4];
      #pragma unroll
      for (int ks = 0; ks < 4; ks++) sa[ks] = (f32x4){0.f, 0.f, 0.f, 0.f};
      #pragma unroll
      for (int s = 0; s < 3; s++)
        #pragma unroll
        for (int ks = 0; ks < 4; ks++) {
          bf16x8 kf = *(const bf16x8*)(Kp + (ks * 16 + ln) * KS_STR + s * 32 + g * 8);
          sa[ks] = MFMA16(kf, qf[s], sa[ks]);
        }
      const bool diag = (k0 + 63 > qw);
      bf16x4 bq[4];
      #pragma unroll
      for (int ks = 0; ks < 4; ks++)
        #pragma unroll
        for (int r = 0; r < 4; r++) {
          float pe = exp2_fast(sa[ks][r]);
          if (diag) {
            int key = k0 + ks * 16 + g * 4 + r;
            if (key > qw + ln) pe = 0.f;
          }
          lsum += pe;
          bq[ks][r] = (__bf16)pe;
        }
      // PV: O^T = V^T . P^T; V fragments for all 4 ks come from 2 b128 reads
      #pragma unroll
      for (int nt = 0; nt < 4; nt++) {
        const __bf16* vb = Vp + (nt * 16 + ln) * VT_STR + g * 16;
        bf16x8 vA = *(const bf16x8*)(vb);       // ks0 | ks1
        bf16x8 vB = *(const bf16x8*)(vb + 8);   // ks2 | ks3
        o[nt] = mfma_pv(__builtin_shufflevector(vA, vA, 0, 1, 2, 3), bq[0], o[nt]);
        o[nt] = mfma_pv(__builtin_shufflevector(vA, vA, 4, 5, 6, 7), bq[1], o[nt]);
        o[nt] = mfma_pv(__builtin_shufflevector(vB, vB, 0, 1, 2, 3), bq[2], o[nt]);
        o[nt] = mfma_pv(__builtin_shufflevector(vB, vB, 4, 5, 6, 7), bq[3], o[nt]);
      }
    }

    if (havenext) {   // write next tile into the other buffer
      *(bf16x8*)(Ksh[p ^ 1] + krow0 * KS_STR + kcol0 * 8) = kreg0;
      if (k1on) *(bf16x8*)(Ksh[p ^ 1] + krow1 * KS_STR + kcol1 * 8) = kreg1;
      __bf16* vd = Vth[p ^ 1] + vr * VT_STR + vpA;
      *(bf16x4*)(vd)      = __builtin_shufflevector(vreg, vreg, 0, 1, 2, 3);
      *(bf16x4*)(vd + 16) = __builtin_shufflevector(vreg, vreg, 4, 5, 6, 7);
    }
    __syncthreads();
    p ^= 1;
  }

  float s = lsum;
  s += __shfl_xor(s, 16);
  s += __shfl_xor(s, 32);
  const float linv = 1.0f / s;

  const size_t obase = (size_t)(bb * T_ + qw + ln) * DM + h * DH;
  #pragma unroll
  for (int nt = 0; nt < 4; nt++) {
    bf16x4 ov = { (__bf16)(o[nt][0] * linv), (__bf16)(o[nt][1] * linv),
                  (__bf16)(o[nt][2] * linv), (__bf16)(o[nt][3] * linv) };
    *(bf16x4*)(ao + obase + nt * 16 + g * 4) = ov;
  }
}

// ---------------------------------------------------------------------------
extern "C" void kernel_launch(void* const* d_in, const int* in_sizes, int n_in,
                              void* d_out, int out_size, void* d_ws, size_t ws_size,
                              hipStream_t stream) {
  const float* x     = (const float*)d_in[0];
  const float* w_dq  = (const float*)d_in[1];
  const float* w_uq  = (const float*)d_in[2];
  const float* w_rq  = (const float*)d_in[3];
  const float* w_dkv = (const float*)d_in[4];
  const float* w_rk  = (const float*)d_in[5];
  const float* w_uk  = (const float*)d_in[6];
  const float* w_uv  = (const float*)d_in[7];
  const float* w_o   = (const float*)d_in[8];
  float* out = (float*)d_out;

  __bf16* p = (__bf16*)d_ws;
  __bf16* xb   = p;  p += (size_t)BT * DM;
  __bf16* B1t  = p;  p += (size_t)672 * 1024;
  __bf16* B2t  = p;  p += (size_t)1536 * 384;
  __bf16* B3t  = p;  p += (size_t)2048 * 256;   // w_uk^T | w_uv^T
  __bf16* B4t  = p;  p += (size_t)1024 * 1024;
  __bf16* cqkr = p;  p += (size_t)BT * 672;     // c_q | c_kv | kr
  __bf16* qsqr = p;  p += (size_t)BT * 1536;    // qs | qr
  __bf16* kv   = p;  p += (size_t)BT * 1024;    // ks
  __bf16* vt   = p;  p += (size_t)BT * 1024;    // V^T [b*1024+h*64+d][T]
  __bf16* qb   = p;  p += (size_t)B_ * NH * T_ * DQK;
  __bf16* kb   = p;  p += (size_t)B_ * NH * T_ * DQK;
  __bf16* aob  = xb;   // xb dead after G1

  // Fused prep: cast x + transpose-cast all 8 weights (one launch)
  {
    TDescs td;
    const float* srcs[8] = {w_dq, w_dkv, w_rk, w_uq, w_rq, w_uk, w_uv, w_o};
    __bf16* dsts[8] = {B1t, B1t + (size_t)384 * 1024, B1t + (size_t)640 * 1024,
                       B2t, B2t + (size_t)1024 * 384,
                       B3t, B3t + (size_t)1024 * 256, B4t};
    int Ks[8] = {1024, 1024, 1024, 384, 384, 256, 256, 1024};
    int Ns[8] = {384, 256, 32, 1024, 512, 1024, 1024, 1024};
    int acc = 0;
    for (int i = 0; i < 8; i++) {
      td.src[i] = srcs[i]; td.dst[i] = dsts[i];
      td.K[i] = Ks[i]; td.N[i] = Ns[i];
      td.t0[i] = acc;
      acc += (Ks[i] / 32) * (Ns[i] / 32);
    }
    td.t0[8] = acc;
    prep_all<<<(BT * DM) / 1024 + acc, 256, 0, stream>>>(x, xb, td);
  }

  // G1: cqkr = xb @ B1t^T   (64x64, BK=64, 4-wave: 704 blocks)  [r14 proven]
  {
    GemmBatch g; g.nd = 1;
    g.d[0] = GemmDesc{xb, B1t, (void*)cqkr, DM, 1024, 672, 1024, 672, 11, 0};
    gemm_multi<__bf16, 64, 64><<<704, 256, 0, stream>>>(g);
  }
  // Fused: G2, G3, VT b0/b1 -> 128x128 tiles (m97 density): 896 blocks
  {
    GemmBatch g; g.nd = 4;
    g.d[0] = GemmDesc{cqkr, B2t, (void*)qsqr, 672, 384, 1536, 384, 1536, 12, 0};
    g.d[1] = GemmDesc{cqkr + 384, B3t, (void*)kv, 672, 256, 1024, 256, 1024, 8, 384};
    g.d[2] = GemmDesc{B3t + (size_t)1024 * 256, cqkr + 384, (void*)vt,
                      256, 672, T_, 256, T_, 16, 640};
    g.d[3] = GemmDesc{B3t + (size_t)1024 * 256, cqkr + (size_t)T_ * 672 + 384,
                      (void*)(vt + (size_t)1024 * T_), 256, 672, T_, 256, T_, 16, 768};
    gemm_multi<__bf16, 128, 128><<<896, 256, 0, stream>>>(g);
  }

  // RoPE + concat + RMS-norm (qb pre-scaled by scale*log2e)
  assemble_qk<<<(BT * NH) / 4, 256, 0, stream>>>(qsqr, kv, cqkr, qb, kb);

  // Paired-tile fixed-max causal MFMA flash attention (8-wave, k-permuted V)
  flash_mfma<<<dim3(T_ / 128, B_ * NH), 512, 0, stream>>>(qb, kb, vt, aob);

  // G4: out = aob @ B4t^T  (fp32 out, 64x64, BK=64, 4-wave: 1024 blocks) [r14]
  {
    GemmBatch g; g.nd = 1;
    g.d[0] = GemmDesc{aob, B4t, (void*)out, DM, 1024, DM, 1024, 1024, 16, 0};
    gemm_multi<float, 64, 64><<<1024, 256, 0, stream>>>(g);
  }
}

// Round 9
// 213.690 us; speedup vs baseline: 1.2403x; 1.0088x over previous
//
#include <hip/hip_runtime.h>
#include <cstdint>
#include <cstddef>
#include <math.h>

#define B_   2
#define T_   2048
#define DM   1024
#define NH   16
#define DH   64
#define DC1  384
#define DCC  256
#define DR   32
#define BT   (B_*T_)
#define DQK  96      // DH + DR

typedef __bf16 bf16x8 __attribute__((ext_vector_type(8)));
typedef __bf16 bf16x4 __attribute__((ext_vector_type(4)));
typedef float  f32x4  __attribute__((ext_vector_type(4)));
typedef short  s16x4  __attribute__((ext_vector_type(4)));
#define MFMA16(a,b,c) __builtin_amdgcn_mfma_f32_16x16x32_bf16((a),(b),(c),0,0,0)

// 16x16x16 bf16 MFMA (K=16): A/B = 4 bf16 (2 VGPR), C/D = 4 f32.
__device__ __forceinline__ f32x4 mfma_pv(bf16x4 a, bf16x4 b, f32x4 c) {
#if __has_builtin(__builtin_amdgcn_mfma_f32_16x16x16bf16_1k)
  return __builtin_amdgcn_mfma_f32_16x16x16bf16_1k(
      __builtin_bit_cast(s16x4, a), __builtin_bit_cast(s16x4, b), c, 0, 0, 0);
#else
  f32x4 d = c;
  asm volatile("v_mfma_f32_16x16x16_bf16 %0, %1, %2, %0"
               : "+v"(d) : "v"(a), "v"(b));
  return d;
#endif
}

__device__ __forceinline__ float exp2_fast(float x) {
#if __has_builtin(__builtin_amdgcn_exp2f)
  return __builtin_amdgcn_exp2f(x);
#else
  float r; asm("v_exp_f32 %0, %1" : "=v"(r) : "v"(x)); return r;
#endif
}

__device__ __forceinline__ void gld16(const __bf16* g, __bf16* l) {
  __builtin_amdgcn_global_load_lds(
      (const __attribute__((address_space(1))) void*)g,
      (__attribute__((address_space(3))) void*)l, 16, 0, 0);
}

struct GemmDesc {
  const __bf16* A;
  const __bf16* Bt;
  void* C;
  int lda, ldb, ldc, K, Nvalid, ntx, blk0;
};
struct GemmBatch { GemmDesc d[4]; int nd; };

// ---------------------------------------------------------------------------
// Multi-GEMM, single-barrier double-buffered gld16 pipeline, BK=64, 4 waves.
// PROVEN CORRECT (r10-r12 bit-identical experiment). TM,TN in {64,128}.
// ---------------------------------------------------------------------------
template<typename CT, int TM, int TN>
__global__ __launch_bounds__(256) void gemm_multi(GemmBatch gb) {
  constexpr int MT  = TM / 32;
  constexpr int NT  = TN / 32;
  constexpr int APW = (TM * 4) / 256;
  constexpr int BPW = (TN * 4) / 256;
  __shared__ __align__(16) __bf16 As[4 * TM * 32];
  __shared__ __align__(16) __bf16 Bs[4 * TN * 32];
  const int bid = blockIdx.x;
  int di = gb.nd - 1;
  while (di > 0 && bid < gb.d[di].blk0) di--;
  const GemmDesc D = gb.d[di];
  const int local = bid - D.blk0;
  const int by = local / D.ntx, bx = local - by * D.ntx;
  const int m0 = by * TM, n0 = bx * TN;

  const int tid = threadIdx.x;
  const int w = tid >> 6, l = tid & 63;
  const int g = l >> 4, ln = l & 15;
  const int wm = w >> 1, wn = w & 1;

  const __bf16* gA[APW]; int aoff[APW];
  #pragma unroll
  for (int i = 0; i < APW; i++) {
    int slot = w * (APW * 64) + i * 64 + l;
    gA[i] = D.A + (size_t)(m0 + (slot >> 2)) * D.lda + (slot & 3) * 8;
    aoff[i] = (w * (APW * 64) + i * 64) * 8;
  }
  const __bf16* gB[BPW]; int boff[BPW];
  #pragma unroll
  for (int i = 0; i < BPW; i++) {
    int slot = w * (BPW * 64) + i * 64 + l;
    int bn = n0 + (slot >> 2); if (bn >= D.Nvalid) bn = D.Nvalid - 1;
    gB[i] = D.Bt + (size_t)bn * D.ldb + (slot & 3) * 8;
    boff[i] = (w * (BPW * 64) + i * 64) * 8;
  }

  f32x4 acc[MT][NT];
  #pragma unroll
  for (int i = 0; i < MT; i++)
    #pragma unroll
    for (int j = 0; j < NT; j++) acc[i][j] = (f32x4){0.f, 0.f, 0.f, 0.f};

  #pragma unroll
  for (int ch = 0; ch < 2; ch++) {
    #pragma unroll
    for (int i = 0; i < APW; i++)
      gld16(gA[i] + ch * 32, As + ch * TM * 32 + aoff[i]);
    #pragma unroll
    for (int i = 0; i < BPW; i++)
      gld16(gB[i] + ch * 32, Bs + ch * TN * 32 + boff[i]);
  }

  const int nper = D.K >> 6;
  int p = 0;
  for (int it = 0; it < nper; ++it) {
    __syncthreads();
    if (it + 1 < nper) {
      const int ko = (it + 1) * 64;
      #pragma unroll
      for (int ch = 0; ch < 2; ch++) {
        #pragma unroll
        for (int i = 0; i < APW; i++)
          gld16(gA[i] + ko + ch * 32, As + ((p ^ 1) * 2 + ch) * TM * 32 + aoff[i]);
        #pragma unroll
        for (int i = 0; i < BPW; i++)
          gld16(gB[i] + ko + ch * 32, Bs + ((p ^ 1) * 2 + ch) * TN * 32 + boff[i]);
      }
    }
    #pragma unroll
    for (int ch = 0; ch < 2; ch++) {
      bf16x8 af[MT], bfr[NT];
      #pragma unroll
      for (int mt = 0; mt < MT; mt++)
        af[mt] = *(const bf16x8*)(As + (p * 2 + ch) * TM * 32 +
                                  (wm * (TM/2) + mt * 16 + ln) * 32 + g * 8);
      #pragma unroll
      for (int nt = 0; nt < NT; nt++)
        bfr[nt] = *(const bf16x8*)(Bs + (p * 2 + ch) * TN * 32 +
                                   (wn * (TN/2) + nt * 16 + ln) * 32 + g * 8);
      #pragma unroll
      for (int mt = 0; mt < MT; mt++)
        #pragma unroll
        for (int nt = 0; nt < NT; nt++)
          acc[mt][nt] = MFMA16(af[mt], bfr[nt], acc[mt][nt]);
    }
    p ^= 1;
  }

  CT* C = (CT*)D.C;
  #pragma unroll
  for (int mt = 0; mt < MT; mt++)
    #pragma unroll
    for (int r = 0; r < 4; r++) {
      int m = m0 + wm * (TM/2) + mt * 16 + g * 4 + r;
      #pragma unroll
      for (int nt = 0; nt < NT; nt++) {
        int n = n0 + wn * (TN/2) + nt * 16 + ln;
        if (n < D.Nvalid) C[(size_t)m * D.ldc + n] = (CT)acc[mt][nt][r];
      }
    }
}

// ---------------------------------------------------------------------------
// Fused prep: cast x -> bf16 AND transpose-cast all 8 weights in ONE launch.
// ---------------------------------------------------------------------------
struct TDescs {
  const float* src[8];
  __bf16* dst[8];
  int K[8];
  int N[8];
  int t0[9];
};

__global__ __launch_bounds__(256) void prep_all(
    const float* __restrict__ x, __bf16* __restrict__ xb, TDescs td) {
  __shared__ float t[32][33];
  const int nCast = (BT * DM) / 1024;   // 4096 blocks of cast work
  if ((int)blockIdx.x < nCast) {
    int i = (blockIdx.x * 256 + threadIdx.x) * 4;
    float4 v = *(const float4*)(x + i);
    bf16x4 o = { (__bf16)v.x, (__bf16)v.y, (__bf16)v.z, (__bf16)v.w };
    *(bf16x4*)(xb + i) = o;
    return;
  }
  int bx = blockIdx.x - nCast;
  int i = 7;
  while (bx < td.t0[i]) i--;
  int local = bx - td.t0[i];
  int ntn = td.N[i] >> 5;
  int kt = local / ntn;
  int nt = local - kt * ntn;
  const int ks = kt * 32, ns = nt * 32;
  const float* src = td.src[i];
  __bf16* dst = td.dst[i];
  const int N = td.N[i], K = td.K[i];
  const int tx = threadIdx.x & 31, ty = threadIdx.x >> 5;
  #pragma unroll
  for (int r = 0; r < 4; r++)
    t[ty + r * 8][tx] = src[(size_t)(ks + ty + r * 8) * N + ns + tx];
  __syncthreads();
  #pragma unroll
  for (int r = 0; r < 4; r++)
    dst[(size_t)(ns + ty + r * 8) * K + ks + tx] = (__bf16)t[tx][ty + r * 8];
}

// ---------------------------------------------------------------------------
// Assemble K only (r24: Q-side fused into flash prologue; qb buffer dead).
// Per (row, head) wave -> RoPE + concat + RMS-norm of k_final.
// ---------------------------------------------------------------------------
__global__ __launch_bounds__(256) void assemble_k(
    const __bf16* __restrict__ kv,    // [BT][1024]: ks
    const __bf16* __restrict__ cqkr,  // [BT][672]: kr at cols 640..671
    __bf16* __restrict__ kb) {
  int wid  = (blockIdx.x * blockDim.x + threadIdx.x) >> 6;
  int lane = threadIdx.x & 63;
  int h   = wid & (NH - 1);
  int row = wid >> 4;
  int b   = row >> 11;
  int t   = row & (T_ - 1);

  float v0k = (float)kv[(size_t)row * 1024 + h * DH + lane];
  float v1k = 0.f;
  if (lane < DR) {
    int j  = lane;
    int jj = j & 15;
    float invf = exp2f((float)jj * -0.8304820237f);  // 10000^(-jj/16)
    float ang  = (float)t * invf;
    float s, c;
    sincosf(ang, &s, &c);
    float kx1 = (float)cqkr[(size_t)row * 672 + 640 + jj];
    float kx2 = (float)cqkr[(size_t)row * 672 + 640 + 16 + jj];
    if (j < 16) v1k = kx1 * c - kx2 * s;
    else        v1k = kx1 * s + kx2 * c;
  }
  float ssk = v0k * v0k + v1k * v1k;
  #pragma unroll
  for (int off = 32; off; off >>= 1)
    ssk += __shfl_xor(ssk, off);
  float sk = rsqrtf(ssk / 96.f + 1e-6f);
  size_t obase = ((size_t)(b * NH + h) * T_ + t) * DQK;
  kb[obase + lane] = (__bf16)(v0k * sk);
  if (lane < DR)
    kb[obase + DH + lane] = (__bf16)(v1k * sk);
}

// ---------------------------------------------------------------------------
// Fixed-max MFMA flash attention (causal), paired q-tiles, 8-wave blocks.
// r20 dbuf single-barrier + r19 swapped-QK reg-P + r23 k-permuted V + exp2.
// r24: Q assembled IN-KERNEL (RoPE + RMS + scale*log2e fold), reading qsqr
//   directly. Q is consumed exactly once per wave -> fusion has zero
//   redundancy (unlike K, re-read ~16x). Kills the qb buffer (12.6 MB
//   write) and halves assemble. Also: lsum split into 2 accumulators
//   (shortens the 16-deep serial add chain per iter).
// ---------------------------------------------------------------------------
#define KS_STR 104   // K LDS row stride
#define VT_STR 72    // V LDS row stride (k-permuted layout, 64 used + 8 pad)
__global__ __launch_bounds__(512) void flash_mfma(
    const __bf16* __restrict__ qg,  // qsqr: [BT][1536] = qs | qr
    const __bf16* __restrict__ kg,
    const __bf16* __restrict__ vt,  // [b*1024 + h*64 + d][T_]  (V^T)
    __bf16* __restrict__ ao) {
  __shared__ __align__(16) __bf16 Ksh[2][64 * KS_STR];   // 2 x 13312 B
  __shared__ __align__(16) __bf16 Vth[2][64 * VT_STR];   // 2 x  9216 B

  // load-balanced remap (r22, neutral but kept): halves complementary in ta
  const int lb   = blockIdx.y * 16 + blockIdx.x;
  const int half = lb >> 8;
  const int i    = lb & 255;
  const int tc   = i & 15;
  const int ta   = half ? (15 - tc) : tc;        // light tile 0..15
  const int hb   = (i >> 4) + half * 16;         // head-batch 0..31
  const int tb   = (T_ / 64 - 1) - ta;           // heavy tile 31..16

  const int bb = hb >> 4, h = hb & 15;
  const int w    = threadIdx.x >> 6;         // 0..7
  const int lane = threadIdx.x & 63;
  const int g    = lane >> 4;
  const int ln   = lane & 15;
  const int wi   = w & 3;
  const int tile = (w < 4) ? tb : ta;        // wave's tile
  const int qw   = tile * 64 + wi * 16;      // wave's 16 queries
  const size_t hbT = (size_t)hb * T_;
  const __bf16* vrow = vt + (size_t)(bb * 1024 + h * 64) * T_;

  const int ks0   = threadIdx.x;
  const int krow0 = ks0 / 12, kcol0 = ks0 % 12;
  const bool k1on = (threadIdx.x < 256);
  const int ks1   = 512 + threadIdx.x;
  const int krow1 = ks1 / 12, kcol1 = ks1 % 12;
  const int vr = threadIdx.x >> 3, vc = threadIdx.x & 7;
  const int vpA = ((vc >> 1) << 2) | ((vc & 1) << 5);   // k-permuted base

  // ---- r24 Q prologue: RoPE + RMS-norm in-register (replaces assemble's q
  //      path). Lane (g,ln) holds 24 of row (qw+ln)'s 96 values; sum-sq
  //      reduces across the 4 g-lanes of each ln via 2 shfl_xor.
  const int tq = qw + ln;
  const size_t qrow = ((size_t)bb * T_ + tq) * 1536;
  bf16x8 qs0 = *(const bf16x8*)(qg + qrow + h * DH + g * 8);
  bf16x8 qs1 = *(const bf16x8*)(qg + qrow + h * DH + 32 + g * 8);
  bf16x8 qlo = *(const bf16x8*)(qg + qrow + 1024 + h * DR + (g & 1) * 8);
  bf16x8 qhi = *(const bf16x8*)(qg + qrow + 1024 + h * DR + 16 + (g & 1) * 8);
  float rot[8];
  float ss = 0.f;
  #pragma unroll
  for (int ii = 0; ii < 8; ii++) {
    int jj = (g & 1) * 8 + ii;
    float invf = exp2f((float)jj * -0.8304820237f);  // 10000^(-jj/16)
    float an = (float)tq * invf;
    float sn, cn;
    sincosf(an, &sn, &cn);
    float lo = (float)qlo[ii], hi = (float)qhi[ii];
    rot[ii] = (g < 2) ? (lo * cn - hi * sn) : (lo * sn + hi * cn);
    float a0 = (float)qs0[ii], a1 = (float)qs1[ii];
    ss += a0 * a0 + a1 * a1 + rot[ii] * rot[ii];
  }
  ss += __shfl_xor(ss, 16);
  ss += __shfl_xor(ss, 32);
  // RMS scale x attention scale(1/sqrt(96)) x log2(e), folded once.
  const float sq = rsqrtf(ss * (1.f / 96.f) + 1e-6f) * 0.14724431f;
  bf16x8 qf[3];
  #pragma unroll
  for (int ii = 0; ii < 8; ii++) {
    qf[0][ii] = (__bf16)((float)qs0[ii] * sq);
    qf[1][ii] = (__bf16)((float)qs1[ii] * sq);
    qf[2][ii] = (__bf16)(rot[ii] * sq);
  }
  // ---- end Q prologue

  f32x4 o[4];
  #pragma unroll
  for (int nt = 0; nt < 4; nt++) o[nt] = (f32x4){0.f, 0.f, 0.f, 0.f};
  float lsum0 = 0.f, lsum1 = 0.f;

  const int kmax = (tb + 1) * 64;

  bf16x8 kreg0, kreg1, vreg;
  // Prologue: tile 0 -> buf 0
  kreg0 = *(const bf16x8*)(kg + (hbT + krow0) * DQK + kcol0 * 8);
  if (k1on) kreg1 = *(const bf16x8*)(kg + (hbT + krow1) * DQK + kcol1 * 8);
  vreg = *(const bf16x8*)(vrow + (size_t)vr * T_ + vc * 8);
  *(bf16x8*)(Ksh[0] + krow0 * KS_STR + kcol0 * 8) = kreg0;
  if (k1on) *(bf16x8*)(Ksh[0] + krow1 * KS_STR + kcol1 * 8) = kreg1;
  {
    __bf16* vd = Vth[0] + vr * VT_STR + vpA;
    *(bf16x4*)(vd)      = __builtin_shufflevector(vreg, vreg, 0, 1, 2, 3);
    *(bf16x4*)(vd + 16) = __builtin_shufflevector(vreg, vreg, 4, 5, 6, 7);
  }
  __syncthreads();

  int p = 0;
  for (int k0 = 0; k0 < kmax; k0 += 64) {
    const bool havenext = (k0 + 64 < kmax);
    if (havenext) {   // prefetch next tile into regs (hidden by compute)
      kreg0 = *(const bf16x8*)(kg + (hbT + k0 + 64 + krow0) * DQK + kcol0 * 8);
      if (k1on)
        kreg1 = *(const bf16x8*)(kg + (hbT + k0 + 64 + krow1) * DQK + kcol1 * 8);
      vreg = *(const bf16x8*)(vrow + (size_t)vr * T_ + k0 + 64 + vc * 8);
    }

    if (k0 <= qw + 15) {   // wave-uniform causal skip
      const __bf16* Kp = Ksh[p];
      const __bf16* Vp = Vth[p];
      // QK^T swapped: sa[ks] = S^T tile, row=key k0+ks*16+g*4+r, col=q=qw+ln
      f32x4 sa[4];
      #pragma unroll
      for (int ks = 0; ks < 4; ks++) sa[ks] = (f32x4){0.f, 0.f, 0.f, 0.f};
      #pragma unroll
      for (int s = 0; s < 3; s++)
        #pragma unroll
        for (int ks = 0; ks < 4; ks++) {
          bf16x8 kf = *(const bf16x8*)(Kp + (ks * 16 + ln) * KS_STR + s * 32 + g * 8);
          sa[ks] = MFMA16(kf, qf[s], sa[ks]);
        }
      const bool diag = (k0 + 63 > qw);
      bf16x4 bq[4];
      #pragma unroll
      for (int ks = 0; ks < 4; ks++)
        #pragma unroll
        for (int r = 0; r < 4; r++) {
          float pe = exp2_fast(sa[ks][r]);
          if (diag) {
            int key = k0 + ks * 16 + g * 4 + r;
            if (key > qw + ln) pe = 0.f;
          }
          if (ks & 2) lsum1 += pe; else lsum0 += pe;
          bq[ks][r] = (__bf16)pe;
        }
      // PV: O^T = V^T . P^T; V fragments for all 4 ks come from 2 b128 reads
      #pragma unroll
      for (int nt = 0; nt < 4; nt++) {
        const __bf16* vb = Vp + (nt * 16 + ln) * VT_STR + g * 16;
        bf16x8 vA = *(const bf16x8*)(vb);       // ks0 | ks1
        bf16x8 vB = *(const bf16x8*)(vb + 8);   // ks2 | ks3
        o[nt] = mfma_pv(__builtin_shufflevector(vA, vA, 0, 1, 2, 3), bq[0], o[nt]);
        o[nt] = mfma_pv(__builtin_shufflevector(vA, vA, 4, 5, 6, 7), bq[1], o[nt]);
        o[nt] = mfma_pv(__builtin_shufflevector(vB, vB, 0, 1, 2, 3), bq[2], o[nt]);
        o[nt] = mfma_pv(__builtin_shufflevector(vB, vB, 4, 5, 6, 7), bq[3], o[nt]);
      }
    }

    if (havenext) {   // write next tile into the other buffer
      *(bf16x8*)(Ksh[p ^ 1] + krow0 * KS_STR + kcol0 * 8) = kreg0;
      if (k1on) *(bf16x8*)(Ksh[p ^ 1] + krow1 * KS_STR + kcol1 * 8) = kreg1;
      __bf16* vd = Vth[p ^ 1] + vr * VT_STR + vpA;
      *(bf16x4*)(vd)      = __builtin_shufflevector(vreg, vreg, 0, 1, 2, 3);
      *(bf16x4*)(vd + 16) = __builtin_shufflevector(vreg, vreg, 4, 5, 6, 7);
    }
    __syncthreads();
    p ^= 1;
  }

  float s = lsum0 + lsum1;
  s += __shfl_xor(s, 16);
  s += __shfl_xor(s, 32);
  const float linv = 1.0f / s;

  const size_t obase = (size_t)(bb * T_ + qw + ln) * DM + h * DH;
  #pragma unroll
  for (int nt = 0; nt < 4; nt++) {
    bf16x4 ov = { (__bf16)(o[nt][0] * linv), (__bf16)(o[nt][1] * linv),
                  (__bf16)(o[nt][2] * linv), (__bf16)(o[nt][3] * linv) };
    *(bf16x4*)(ao + obase + nt * 16 + g * 4) = ov;
  }
}

// ---------------------------------------------------------------------------
extern "C" void kernel_launch(void* const* d_in, const int* in_sizes, int n_in,
                              void* d_out, int out_size, void* d_ws, size_t ws_size,
                              hipStream_t stream) {
  const float* x     = (const float*)d_in[0];
  const float* w_dq  = (const float*)d_in[1];
  const float* w_uq  = (const float*)d_in[2];
  const float* w_rq  = (const float*)d_in[3];
  const float* w_dkv = (const float*)d_in[4];
  const float* w_rk  = (const float*)d_in[5];
  const float* w_uk  = (const float*)d_in[6];
  const float* w_uv  = (const float*)d_in[7];
  const float* w_o   = (const float*)d_in[8];
  float* out = (float*)d_out;

  __bf16* p = (__bf16*)d_ws;
  __bf16* xb   = p;  p += (size_t)BT * DM;
  __bf16* B1t  = p;  p += (size_t)672 * 1024;
  __bf16* B2t  = p;  p += (size_t)1536 * 384;
  __bf16* B3t  = p;  p += (size_t)2048 * 256;   // w_uk^T | w_uv^T
  __bf16* B4t  = p;  p += (size_t)1024 * 1024;
  __bf16* cqkr = p;  p += (size_t)BT * 672;     // c_q | c_kv | kr
  __bf16* qsqr = p;  p += (size_t)BT * 1536;    // qs | qr (read by flash r24)
  __bf16* kv   = p;  p += (size_t)BT * 1024;    // ks
  __bf16* vt   = p;  p += (size_t)BT * 1024;    // V^T [b*1024+h*64+d][T]
  __bf16* kb   = p;  p += (size_t)B_ * NH * T_ * DQK;
  __bf16* aob  = xb;   // xb dead after G1

  // Fused prep: cast x + transpose-cast all 8 weights (one launch)
  {
    TDescs td;
    const float* srcs[8] = {w_dq, w_dkv, w_rk, w_uq, w_rq, w_uk, w_uv, w_o};
    __bf16* dsts[8] = {B1t, B1t + (size_t)384 * 1024, B1t + (size_t)640 * 1024,
                       B2t, B2t + (size_t)1024 * 384,
                       B3t, B3t + (size_t)1024 * 256, B4t};
    int Ks[8] = {1024, 1024, 1024, 384, 384, 256, 256, 1024};
    int Ns[8] = {384, 256, 32, 1024, 512, 1024, 1024, 1024};
    int acc = 0;
    for (int i = 0; i < 8; i++) {
      td.src[i] = srcs[i]; td.dst[i] = dsts[i];
      td.K[i] = Ks[i]; td.N[i] = Ns[i];
      td.t0[i] = acc;
      acc += (Ks[i] / 32) * (Ns[i] / 32);
    }
    td.t0[8] = acc;
    prep_all<<<(BT * DM) / 1024 + acc, 256, 0, stream>>>(x, xb, td);
  }

  // G1: cqkr = xb @ B1t^T   (64x64, BK=64, 4-wave: 704 blocks)  [r14 proven]
  {
    GemmBatch g; g.nd = 1;
    g.d[0] = GemmDesc{xb, B1t, (void*)cqkr, DM, 1024, 672, 1024, 672, 11, 0};
    gemm_multi<__bf16, 64, 64><<<704, 256, 0, stream>>>(g);
  }
  // Fused: G2, G3, VT b0/b1 -> 128x128 tiles (m97 density): 896 blocks
  {
    GemmBatch g; g.nd = 4;
    g.d[0] = GemmDesc{cqkr, B2t, (void*)qsqr, 672, 384, 1536, 384, 1536, 12, 0};
    g.d[1] = GemmDesc{cqkr + 384, B3t, (void*)kv, 672, 256, 1024, 256, 1024, 8, 384};
    g.d[2] = GemmDesc{B3t + (size_t)1024 * 256, cqkr + 384, (void*)vt,
                      256, 672, T_, 256, T_, 16, 640};
    g.d[3] = GemmDesc{B3t + (size_t)1024 * 256, cqkr + (size_t)T_ * 672 + 384,
                      (void*)(vt + (size_t)1024 * T_), 256, 672, T_, 256, T_, 16, 768};
    gemm_multi<__bf16, 128, 128><<<896, 256, 0, stream>>>(g);
  }

  // RoPE + concat + RMS-norm for K only (Q fused into flash)
  assemble_k<<<(BT * NH) / 4, 256, 0, stream>>>(kv, cqkr, kb);

  // Paired-tile fixed-max causal MFMA flash attention (8-wave, in-kernel Q)
  flash_mfma<<<dim3(T_ / 128, B_ * NH), 512, 0, stream>>>(qsqr, kb, vt, aob);

  // G4: out = aob @ B4t^T  (fp32 out, 64x64, BK=64, 4-wave: 1024 blocks) [r14]
  {
    GemmBatch g; g.nd = 1;
    g.d[0] = GemmDesc{aob, B4t, (void*)out, DM, 1024, DM, 1024, 1024, 16, 0};
    gemm_multi<float, 64, 64><<<1024, 256, 0, stream>>>(g);
  }
}

// Round 10
// 213.292 us; speedup vs baseline: 1.2426x; 1.0019x over previous
//
#include <hip/hip_runtime.h>
#include <cstdint>
#include <cstddef>
#include <math.h>

#define B_   2
#define T_   2048
#define DM   1024
#define NH   16
#define DH   64
#define DC1  384
#define DCC  256
#define DR   32
#define BT   (B_*T_)
#define DQK  96      // DH + DR

typedef __bf16 bf16x8 __attribute__((ext_vector_type(8)));
typedef __bf16 bf16x4 __attribute__((ext_vector_type(4)));
typedef float  f32x4  __attribute__((ext_vector_type(4)));
typedef short  s16x4  __attribute__((ext_vector_type(4)));
#define MFMA16(a,b,c) __builtin_amdgcn_mfma_f32_16x16x32_bf16((a),(b),(c),0,0,0)

// 16x16x16 bf16 MFMA (K=16): A/B = 4 bf16 (2 VGPR), C/D = 4 f32.
__device__ __forceinline__ f32x4 mfma_pv(bf16x4 a, bf16x4 b, f32x4 c) {
#if __has_builtin(__builtin_amdgcn_mfma_f32_16x16x16bf16_1k)
  return __builtin_amdgcn_mfma_f32_16x16x16bf16_1k(
      __builtin_bit_cast(s16x4, a), __builtin_bit_cast(s16x4, b), c, 0, 0, 0);
#else
  f32x4 d = c;
  asm volatile("v_mfma_f32_16x16x16_bf16 %0, %1, %2, %0"
               : "+v"(d) : "v"(a), "v"(b));
  return d;
#endif
}

__device__ __forceinline__ float exp2_fast(float x) {
#if __has_builtin(__builtin_amdgcn_exp2f)
  return __builtin_amdgcn_exp2f(x);
#else
  float r; asm("v_exp_f32 %0, %1" : "=v"(r) : "v"(x)); return r;
#endif
}

__device__ __forceinline__ void gld16(const __bf16* g, __bf16* l) {
  __builtin_amdgcn_global_load_lds(
      (const __attribute__((address_space(1))) void*)g,
      (__attribute__((address_space(3))) void*)l, 16, 0, 0);
}

struct GemmDesc {
  const __bf16* A;
  const __bf16* Bt;
  void* C;
  int lda, ldb, ldc, K, Nvalid, ntx, blk0;
};
struct GemmBatch { GemmDesc d[4]; int nd; };

// ---------------------------------------------------------------------------
// Multi-GEMM, single-barrier double-buffered gld16 pipeline, BK=64, 4 waves.
// PROVEN CORRECT (r10-r12 bit-identical experiment). TM,TN in {64,128}.
// ---------------------------------------------------------------------------
template<typename CT, int TM, int TN>
__global__ __launch_bounds__(256) void gemm_multi(GemmBatch gb) {
  constexpr int MT  = TM / 32;
  constexpr int NT  = TN / 32;
  constexpr int APW = (TM * 4) / 256;
  constexpr int BPW = (TN * 4) / 256;
  __shared__ __align__(16) __bf16 As[4 * TM * 32];
  __shared__ __align__(16) __bf16 Bs[4 * TN * 32];
  const int bid = blockIdx.x;
  int di = gb.nd - 1;
  while (di > 0 && bid < gb.d[di].blk0) di--;
  const GemmDesc D = gb.d[di];
  const int local = bid - D.blk0;
  const int by = local / D.ntx, bx = local - by * D.ntx;
  const int m0 = by * TM, n0 = bx * TN;

  const int tid = threadIdx.x;
  const int w = tid >> 6, l = tid & 63;
  const int g = l >> 4, ln = l & 15;
  const int wm = w >> 1, wn = w & 1;

  const __bf16* gA[APW]; int aoff[APW];
  #pragma unroll
  for (int i = 0; i < APW; i++) {
    int slot = w * (APW * 64) + i * 64 + l;
    gA[i] = D.A + (size_t)(m0 + (slot >> 2)) * D.lda + (slot & 3) * 8;
    aoff[i] = (w * (APW * 64) + i * 64) * 8;
  }
  const __bf16* gB[BPW]; int boff[BPW];
  #pragma unroll
  for (int i = 0; i < BPW; i++) {
    int slot = w * (BPW * 64) + i * 64 + l;
    int bn = n0 + (slot >> 2); if (bn >= D.Nvalid) bn = D.Nvalid - 1;
    gB[i] = D.Bt + (size_t)bn * D.ldb + (slot & 3) * 8;
    boff[i] = (w * (BPW * 64) + i * 64) * 8;
  }

  f32x4 acc[MT][NT];
  #pragma unroll
  for (int i = 0; i < MT; i++)
    #pragma unroll
    for (int j = 0; j < NT; j++) acc[i][j] = (f32x4){0.f, 0.f, 0.f, 0.f};

  #pragma unroll
  for (int ch = 0; ch < 2; ch++) {
    #pragma unroll
    for (int i = 0; i < APW; i++)
      gld16(gA[i] + ch * 32, As + ch * TM * 32 + aoff[i]);
    #pragma unroll
    for (int i = 0; i < BPW; i++)
      gld16(gB[i] + ch * 32, Bs + ch * TN * 32 + boff[i]);
  }

  const int nper = D.K >> 6;
  int p = 0;
  for (int it = 0; it < nper; ++it) {
    __syncthreads();
    if (it + 1 < nper) {
      const int ko = (it + 1) * 64;
      #pragma unroll
      for (int ch = 0; ch < 2; ch++) {
        #pragma unroll
        for (int i = 0; i < APW; i++)
          gld16(gA[i] + ko + ch * 32, As + ((p ^ 1) * 2 + ch) * TM * 32 + aoff[i]);
        #pragma unroll
        for (int i = 0; i < BPW; i++)
          gld16(gB[i] + ko + ch * 32, Bs + ((p ^ 1) * 2 + ch) * TN * 32 + boff[i]);
      }
    }
    #pragma unroll
    for (int ch = 0; ch < 2; ch++) {
      bf16x8 af[MT], bfr[NT];
      #pragma unroll
      for (int mt = 0; mt < MT; mt++)
        af[mt] = *(const bf16x8*)(As + (p * 2 + ch) * TM * 32 +
                                  (wm * (TM/2) + mt * 16 + ln) * 32 + g * 8);
      #pragma unroll
      for (int nt = 0; nt < NT; nt++)
        bfr[nt] = *(const bf16x8*)(Bs + (p * 2 + ch) * TN * 32 +
                                   (wn * (TN/2) + nt * 16 + ln) * 32 + g * 8);
      #pragma unroll
      for (int mt = 0; mt < MT; mt++)
        #pragma unroll
        for (int nt = 0; nt < NT; nt++)
          acc[mt][nt] = MFMA16(af[mt], bfr[nt], acc[mt][nt]);
    }
    p ^= 1;
  }

  CT* C = (CT*)D.C;
  #pragma unroll
  for (int mt = 0; mt < MT; mt++)
    #pragma unroll
    for (int r = 0; r < 4; r++) {
      int m = m0 + wm * (TM/2) + mt * 16 + g * 4 + r;
      #pragma unroll
      for (int nt = 0; nt < NT; nt++) {
        int n = n0 + wn * (TN/2) + nt * 16 + ln;
        if (n < D.Nvalid) C[(size_t)m * D.ldc + n] = (CT)acc[mt][nt][r];
      }
    }
}

// ---------------------------------------------------------------------------
// Fused prep: cast x -> bf16, build RoPE cos/sin table, transpose-cast all 8
// weights -- ONE launch (independent work; branch on blockIdx range).
// r25: tab[t][jj] = (cos, sin) of t * 10000^(-jj/16). 256 KB, L2-resident,
// shared by flash prologue (was 8 sincosf/lane -> VALU bubble, +4.6 us r24)
// and assemble_k. Same sincosf values -> bit-identical results.
// ---------------------------------------------------------------------------
struct TDescs {
  const float* src[8];
  __bf16* dst[8];
  int K[8];
  int N[8];
  int t0[9];
};

__global__ __launch_bounds__(256) void prep_all(
    const float* __restrict__ x, __bf16* __restrict__ xb,
    float2* __restrict__ rope, TDescs td) {
  __shared__ float t[32][33];
  const int nCast = (BT * DM) / 1024;   // 4096 blocks of cast work
  const int nTab  = (T_ * 16) / 256;    // 128 blocks of table work
  if ((int)blockIdx.x < nCast) {
    int i = (blockIdx.x * 256 + threadIdx.x) * 4;
    float4 v = *(const float4*)(x + i);
    bf16x4 o = { (__bf16)v.x, (__bf16)v.y, (__bf16)v.z, (__bf16)v.w };
    *(bf16x4*)(xb + i) = o;
    return;
  }
  if ((int)blockIdx.x < nCast + nTab) {
    int idx = (blockIdx.x - nCast) * 256 + threadIdx.x;  // 0..32767
    int tt = idx >> 4, jj = idx & 15;
    float invf = exp2f((float)jj * -0.8304820237f);      // 10000^(-jj/16)
    float ang = (float)tt * invf;
    float s, c;
    sincosf(ang, &s, &c);
    rope[idx] = make_float2(c, s);
    return;
  }
  int bx = blockIdx.x - nCast - nTab;
  int i = 7;
  while (bx < td.t0[i]) i--;
  int local = bx - td.t0[i];
  int ntn = td.N[i] >> 5;
  int kt = local / ntn;
  int nt = local - kt * ntn;
  const int ks = kt * 32, ns = nt * 32;
  const float* src = td.src[i];
  __bf16* dst = td.dst[i];
  const int N = td.N[i], K = td.K[i];
  const int tx = threadIdx.x & 31, ty = threadIdx.x >> 5;
  #pragma unroll
  for (int r = 0; r < 4; r++)
    t[ty + r * 8][tx] = src[(size_t)(ks + ty + r * 8) * N + ns + tx];
  __syncthreads();
  #pragma unroll
  for (int r = 0; r < 4; r++)
    dst[(size_t)(ns + ty + r * 8) * K + ks + tx] = (__bf16)t[tx][ty + r * 8];
}

// ---------------------------------------------------------------------------
// Assemble K only. r25: RoPE angles from table (no per-lane trig).
// ---------------------------------------------------------------------------
__global__ __launch_bounds__(256) void assemble_k(
    const __bf16* __restrict__ kv,    // [BT][1024]: ks
    const __bf16* __restrict__ cqkr,  // [BT][672]: kr at cols 640..671
    const float2* __restrict__ rope,
    __bf16* __restrict__ kb) {
  int wid  = (blockIdx.x * blockDim.x + threadIdx.x) >> 6;
  int lane = threadIdx.x & 63;
  int h   = wid & (NH - 1);
  int row = wid >> 4;
  int b   = row >> 11;
  int t   = row & (T_ - 1);

  float v0k = (float)kv[(size_t)row * 1024 + h * DH + lane];
  float v1k = 0.f;
  if (lane < DR) {
    int jj = lane & 15;
    float2 cs = rope[t * 16 + jj];
    float kx1 = (float)cqkr[(size_t)row * 672 + 640 + jj];
    float kx2 = (float)cqkr[(size_t)row * 672 + 640 + 16 + jj];
    if (lane < 16) v1k = kx1 * cs.x - kx2 * cs.y;
    else           v1k = kx1 * cs.y + kx2 * cs.x;
  }
  float ssk = v0k * v0k + v1k * v1k;
  #pragma unroll
  for (int off = 32; off; off >>= 1)
    ssk += __shfl_xor(ssk, off);
  float sk = rsqrtf(ssk / 96.f + 1e-6f);
  size_t obase = ((size_t)(b * NH + h) * T_ + t) * DQK;
  kb[obase + lane] = (__bf16)(v0k * sk);
  if (lane < DR)
    kb[obase + DH + lane] = (__bf16)(v1k * sk);
}

// ---------------------------------------------------------------------------
// Fixed-max MFMA flash attention (causal), paired q-tiles, 8-wave blocks.
// r20 dbuf single-barrier + r19 swapped-QK reg-P + r23 k-permuted V + exp2.
// r24: Q assembled in-kernel (zero-redundancy fusion; qb buffer dead).
// r25: Q prologue RoPE angles from the rope table -- replaces 8 sincosf +
//   8 exp2f per lane (the r24 +4.6us VALU bubble) with 8 float2 loads
//   (64 B/lane, coalesced, L2-hot: table is 256 KB shared by all blocks).
// ---------------------------------------------------------------------------
#define KS_STR 104   // K LDS row stride
#define VT_STR 72    // V LDS row stride (k-permuted layout, 64 used + 8 pad)
__global__ __launch_bounds__(512) void flash_mfma(
    const __bf16* __restrict__ qg,  // qsqr: [BT][1536] = qs | qr
    const __bf16* __restrict__ kg,
    const __bf16* __restrict__ vt,  // [b*1024 + h*64 + d][T_]  (V^T)
    const float2* __restrict__ rope,
    __bf16* __restrict__ ao) {
  __shared__ __align__(16) __bf16 Ksh[2][64 * KS_STR];   // 2 x 13312 B
  __shared__ __align__(16) __bf16 Vth[2][64 * VT_STR];   // 2 x  9216 B

  // load-balanced remap (r22, neutral but kept): halves complementary in ta
  const int lb   = blockIdx.y * 16 + blockIdx.x;
  const int half = lb >> 8;
  const int i    = lb & 255;
  const int tc   = i & 15;
  const int ta   = half ? (15 - tc) : tc;        // light tile 0..15
  const int hb   = (i >> 4) + half * 16;         // head-batch 0..31
  const int tb   = (T_ / 64 - 1) - ta;           // heavy tile 31..16

  const int bb = hb >> 4, h = hb & 15;
  const int w    = threadIdx.x >> 6;         // 0..7
  const int lane = threadIdx.x & 63;
  const int g    = lane >> 4;
  const int ln   = lane & 15;
  const int wi   = w & 3;
  const int tile = (w < 4) ? tb : ta;        // wave's tile
  const int qw   = tile * 64 + wi * 16;      // wave's 16 queries
  const size_t hbT = (size_t)hb * T_;
  const __bf16* vrow = vt + (size_t)(bb * 1024 + h * 64) * T_;

  const int ks0   = threadIdx.x;
  const int krow0 = ks0 / 12, kcol0 = ks0 % 12;
  const bool k1on = (threadIdx.x < 256);
  const int ks1   = 512 + threadIdx.x;
  const int krow1 = ks1 / 12, kcol1 = ks1 % 12;
  const int vr = threadIdx.x >> 3, vc = threadIdx.x & 7;
  const int vpA = ((vc >> 1) << 2) | ((vc & 1) << 5);   // k-permuted base

  // ---- Q prologue: RoPE (table) + RMS-norm in-register.
  const int tq = qw + ln;
  const size_t qrow = ((size_t)bb * T_ + tq) * 1536;
  bf16x8 qs0 = *(const bf16x8*)(qg + qrow + h * DH + g * 8);
  bf16x8 qs1 = *(const bf16x8*)(qg + qrow + h * DH + 32 + g * 8);
  bf16x8 qlo = *(const bf16x8*)(qg + qrow + 1024 + h * DR + (g & 1) * 8);
  bf16x8 qhi = *(const bf16x8*)(qg + qrow + 1024 + h * DR + 16 + (g & 1) * 8);
  const float2* tr = rope + tq * 16 + (g & 1) * 8;
  float rot[8];
  float ss = 0.f;
  #pragma unroll
  for (int ii = 0; ii < 8; ii++) {
    float2 cs = tr[ii];
    float lo = (float)qlo[ii], hi = (float)qhi[ii];
    rot[ii] = (g < 2) ? (lo * cs.x - hi * cs.y) : (lo * cs.y + hi * cs.x);
    float a0 = (float)qs0[ii], a1 = (float)qs1[ii];
    ss += a0 * a0 + a1 * a1 + rot[ii] * rot[ii];
  }
  ss += __shfl_xor(ss, 16);
  ss += __shfl_xor(ss, 32);
  // RMS scale x attention scale(1/sqrt(96)) x log2(e), folded once.
  const float sq = rsqrtf(ss * (1.f / 96.f) + 1e-6f) * 0.14724431f;
  bf16x8 qf[3];
  #pragma unroll
  for (int ii = 0; ii < 8; ii++) {
    qf[0][ii] = (__bf16)((float)qs0[ii] * sq);
    qf[1][ii] = (__bf16)((float)qs1[ii] * sq);
    qf[2][ii] = (__bf16)(rot[ii] * sq);
  }
  // ---- end Q prologue

  f32x4 o[4];
  #pragma unroll
  for (int nt = 0; nt < 4; nt++) o[nt] = (f32x4){0.f, 0.f, 0.f, 0.f};
  float lsum0 = 0.f, lsum1 = 0.f;

  const int kmax = (tb + 1) * 64;

  bf16x8 kreg0, kreg1, vreg;
  // Prologue: tile 0 -> buf 0
  kreg0 = *(const bf16x8*)(kg + (hbT + krow0) * DQK + kcol0 * 8);
  if (k1on) kreg1 = *(const bf16x8*)(kg + (hbT + krow1) * DQK + kcol1 * 8);
  vreg = *(const bf16x8*)(vrow + (size_t)vr * T_ + vc * 8);
  *(bf16x8*)(Ksh[0] + krow0 * KS_STR + kcol0 * 8) = kreg0;
  if (k1on) *(bf16x8*)(Ksh[0] + krow1 * KS_STR + kcol1 * 8) = kreg1;
  {
    __bf16* vd = Vth[0] + vr * VT_STR + vpA;
    *(bf16x4*)(vd)      = __builtin_shufflevector(vreg, vreg, 0, 1, 2, 3);
    *(bf16x4*)(vd + 16) = __builtin_shufflevector(vreg, vreg, 4, 5, 6, 7);
  }
  __syncthreads();

  int p = 0;
  for (int k0 = 0; k0 < kmax; k0 += 64) {
    const bool havenext = (k0 + 64 < kmax);
    if (havenext) {   // prefetch next tile into regs (hidden by compute)
      kreg0 = *(const bf16x8*)(kg + (hbT + k0 + 64 + krow0) * DQK + kcol0 * 8);
      if (k1on)
        kreg1 = *(const bf16x8*)(kg + (hbT + k0 + 64 + krow1) * DQK + kcol1 * 8);
      vreg = *(const bf16x8*)(vrow + (size_t)vr * T_ + k0 + 64 + vc * 8);
    }

    if (k0 <= qw + 15) {   // wave-uniform causal skip
      const __bf16* Kp = Ksh[p];
      const __bf16* Vp = Vth[p];
      // QK^T swapped: sa[ks] = S^T tile, row=key k0+ks*16+g*4+r, col=q=qw+ln
      f32x4 sa[4];
      #pragma unroll
      for (int ks = 0; ks < 4; ks++) sa[ks] = (f32x4){0.f, 0.f, 0.f, 0.f};
      #pragma unroll
      for (int s = 0; s < 3; s++)
        #pragma unroll
        for (int ks = 0; ks < 4; ks++) {
          bf16x8 kf = *(const bf16x8*)(Kp + (ks * 16 + ln) * KS_STR + s * 32 + g * 8);
          sa[ks] = MFMA16(kf, qf[s], sa[ks]);
        }
      const bool diag = (k0 + 63 > qw);
      bf16x4 bq[4];
      #pragma unroll
      for (int ks = 0; ks < 4; ks++)
        #pragma unroll
        for (int r = 0; r < 4; r++) {
          float pe = exp2_fast(sa[ks][r]);
          if (diag) {
            int key = k0 + ks * 16 + g * 4 + r;
            if (key > qw + ln) pe = 0.f;
          }
          if (ks & 2) lsum1 += pe; else lsum0 += pe;
          bq[ks][r] = (__bf16)pe;
        }
      // PV: O^T = V^T . P^T; V fragments for all 4 ks come from 2 b128 reads
      #pragma unroll
      for (int nt = 0; nt < 4; nt++) {
        const __bf16* vb = Vp + (nt * 16 + ln) * VT_STR + g * 16;
        bf16x8 vA = *(const bf16x8*)(vb);       // ks0 | ks1
        bf16x8 vB = *(const bf16x8*)(vb + 8);   // ks2 | ks3
        o[nt] = mfma_pv(__builtin_shufflevector(vA, vA, 0, 1, 2, 3), bq[0], o[nt]);
        o[nt] = mfma_pv(__builtin_shufflevector(vA, vA, 4, 5, 6, 7), bq[1], o[nt]);
        o[nt] = mfma_pv(__builtin_shufflevector(vB, vB, 0, 1, 2, 3), bq[2], o[nt]);
        o[nt] = mfma_pv(__builtin_shufflevector(vB, vB, 4, 5, 6, 7), bq[3], o[nt]);
      }
    }

    if (havenext) {   // write next tile into the other buffer
      *(bf16x8*)(Ksh[p ^ 1] + krow0 * KS_STR + kcol0 * 8) = kreg0;
      if (k1on) *(bf16x8*)(Ksh[p ^ 1] + krow1 * KS_STR + kcol1 * 8) = kreg1;
      __bf16* vd = Vth[p ^ 1] + vr * VT_STR + vpA;
      *(bf16x4*)(vd)      = __builtin_shufflevector(vreg, vreg, 0, 1, 2, 3);
      *(bf16x4*)(vd + 16) = __builtin_shufflevector(vreg, vreg, 4, 5, 6, 7);
    }
    __syncthreads();
    p ^= 1;
  }

  float s = lsum0 + lsum1;
  s += __shfl_xor(s, 16);
  s += __shfl_xor(s, 32);
  const float linv = 1.0f / s;

  const size_t obase = (size_t)(bb * T_ + qw + ln) * DM + h * DH;
  #pragma unroll
  for (int nt = 0; nt < 4; nt++) {
    bf16x4 ov = { (__bf16)(o[nt][0] * linv), (__bf16)(o[nt][1] * linv),
                  (__bf16)(o[nt][2] * linv), (__bf16)(o[nt][3] * linv) };
    *(bf16x4*)(ao + obase + nt * 16 + g * 4) = ov;
  }
}

// ---------------------------------------------------------------------------
extern "C" void kernel_launch(void* const* d_in, const int* in_sizes, int n_in,
                              void* d_out, int out_size, void* d_ws, size_t ws_size,
                              hipStream_t stream) {
  const float* x     = (const float*)d_in[0];
  const float* w_dq  = (const float*)d_in[1];
  const float* w_uq  = (const float*)d_in[2];
  const float* w_rq  = (const float*)d_in[3];
  const float* w_dkv = (const float*)d_in[4];
  const float* w_rk  = (const float*)d_in[5];
  const float* w_uk  = (const float*)d_in[6];
  const float* w_uv  = (const float*)d_in[7];
  const float* w_o   = (const float*)d_in[8];
  float* out = (float*)d_out;

  __bf16* p = (__bf16*)d_ws;
  __bf16* xb   = p;  p += (size_t)BT * DM;
  __bf16* B1t  = p;  p += (size_t)672 * 1024;
  __bf16* B2t  = p;  p += (size_t)1536 * 384;
  __bf16* B3t  = p;  p += (size_t)2048 * 256;   // w_uk^T | w_uv^T
  __bf16* B4t  = p;  p += (size_t)1024 * 1024;
  __bf16* cqkr = p;  p += (size_t)BT * 672;     // c_q | c_kv | kr
  __bf16* qsqr = p;  p += (size_t)BT * 1536;    // qs | qr (read by flash)
  __bf16* kv   = p;  p += (size_t)BT * 1024;    // ks
  __bf16* vt   = p;  p += (size_t)BT * 1024;    // V^T [b*1024+h*64+d][T]
  __bf16* kb   = p;  p += (size_t)B_ * NH * T_ * DQK;
  float2* rope = (float2*)p;  p += (size_t)T_ * 16 * 4;  // 256 KB table
  __bf16* aob  = xb;   // xb dead after G1

  // Fused prep: cast x + RoPE table + transpose-cast all 8 weights
  {
    TDescs td;
    const float* srcs[8] = {w_dq, w_dkv, w_rk, w_uq, w_rq, w_uk, w_uv, w_o};
    __bf16* dsts[8] = {B1t, B1t + (size_t)384 * 1024, B1t + (size_t)640 * 1024,
                       B2t, B2t + (size_t)1024 * 384,
                       B3t, B3t + (size_t)1024 * 256, B4t};
    int Ks[8] = {1024, 1024, 1024, 384, 384, 256, 256, 1024};
    int Ns[8] = {384, 256, 32, 1024, 512, 1024, 1024, 1024};
    int acc = 0;
    for (int i = 0; i < 8; i++) {
      td.src[i] = srcs[i]; td.dst[i] = dsts[i];
      td.K[i] = Ks[i]; td.N[i] = Ns[i];
      td.t0[i] = acc;
      acc += (Ks[i] / 32) * (Ns[i] / 32);
    }
    td.t0[8] = acc;
    prep_all<<<(BT * DM) / 1024 + (T_ * 16) / 256 + acc, 256, 0, stream>>>(
        x, xb, rope, td);
  }

  // G1: cqkr = xb @ B1t^T   (64x64, BK=64, 4-wave: 704 blocks)  [r14 proven]
  {
    GemmBatch g; g.nd = 1;
    g.d[0] = GemmDesc{xb, B1t, (void*)cqkr, DM, 1024, 672, 1024, 672, 11, 0};
    gemm_multi<__bf16, 64, 64><<<704, 256, 0, stream>>>(g);
  }
  // Fused: G2, G3, VT b0/b1 -> 128x128 tiles (m97 density): 896 blocks
  {
    GemmBatch g; g.nd = 4;
    g.d[0] = GemmDesc{cqkr, B2t, (void*)qsqr, 672, 384, 1536, 384, 1536, 12, 0};
    g.d[1] = GemmDesc{cqkr + 384, B3t, (void*)kv, 672, 256, 1024, 256, 1024, 8, 384};
    g.d[2] = GemmDesc{B3t + (size_t)1024 * 256, cqkr + 384, (void*)vt,
                      256, 672, T_, 256, T_, 16, 640};
    g.d[3] = GemmDesc{B3t + (size_t)1024 * 256, cqkr + (size_t)T_ * 672 + 384,
                      (void*)(vt + (size_t)1024 * T_), 256, 672, T_, 256, T_, 16, 768};
    gemm_multi<__bf16, 128, 128><<<896, 256, 0, stream>>>(g);
  }

  // RoPE + concat + RMS-norm for K only (Q fused into flash; table-driven)
  assemble_k<<<(BT * NH) / 4, 256, 0, stream>>>(kv, cqkr, rope, kb);

  // Paired-tile fixed-max causal MFMA flash attention (8-wave, table-Q)
  flash_mfma<<<dim3(T_ / 128, B_ * NH), 512, 0, stream>>>(qsqr, kb, vt, rope, aob);

  // G4: out = aob @ B4t^T  (fp32 out, 64x64, BK=64, 4-wave: 1024 blocks) [r14]
  {
    GemmBatch g; g.nd = 1;
    g.d[0] = GemmDesc{aob, B4t, (void*)out, DM, 1024, DM, 1024, 1024, 16, 0};
    gemm_multi<float, 64, 64><<<1024, 256, 0, stream>>>(g);
  }
}